// Round 8
// baseline (643.742 us; speedup 1.0000x reference)
//
#include <hip/hip_runtime.h>
#include <hip/hip_bf16.h>

#define S_LEN 4096
#define DMODEL 2048
#define NHEADS 16
#define HEADDIM 128

typedef __attribute__((ext_vector_type(8))) short bf16x8;
typedef __attribute__((ext_vector_type(4))) float f32x4;

__device__ __forceinline__ float bf2f(ushort u) {
  union { unsigned int i; float f; } x; x.i = ((unsigned int)u) << 16; return x.f;
}
__device__ __forceinline__ ushort f2bf(float f) {
  union { float f; unsigned int i; } x; x.f = f;
  unsigned int u = x.i;
  unsigned int r = u + 0x7fffu + ((u >> 16) & 1u);
  return (ushort)(r >> 16);
}
__device__ __forceinline__ void splitf(float f, ushort& h, ushort& l) {
  unsigned int u = __float_as_uint(f);
  h = (ushort)(u >> 16);
  l = f2bf(f - __uint_as_float(u & 0xffff0000u));
}
__device__ __forceinline__ unsigned int cvtpk(float a, float b) {
  unsigned int r;
  asm("v_cvt_pk_bf16_f32 %0, %1, %2" : "=v"(r) : "v"(a), "v"(b));
  return r;
}

__device__ __forceinline__ void gload16(const ushort* g, ushort* l) {
  __builtin_amdgcn_global_load_lds(
      (const __attribute__((address_space(1))) unsigned int*)g,
      (__attribute__((address_space(3))) unsigned int*)l, 16, 0, 0);
}

// ---------------- RoPE cos/sin table ----------------
__global__ __launch_bounds__(256) void rope_table_kernel(float* __restrict__ cosT,
                                                         float* __restrict__ sinT) {
  int idx = blockIdx.x * 256 + threadIdx.x;
  int t = idx >> 6, j = idx & 63;
  float expo = (float)(2 * j) / 128.0f;
  float inv = 1.0f / powf(10000.0f, expo);
  float f = (float)t * inv;
  cosT[idx] = cosf(f);
  sinT[idx] = sinf(f);
}

// ---------------- fp32 -> bf16 (RNE) convert ----------------
__global__ __launch_bounds__(256) void convert_kernel(const float* __restrict__ in,
                                                      ushort* __restrict__ hi) {
  int i = (blockIdx.x * 256 + threadIdx.x) * 4;
  float4 v = *reinterpret_cast<const float4*>(&in[i]);
  ushort4 h;
  h.x = f2bf(v.x); h.y = f2bf(v.y); h.z = f2bf(v.z); h.w = f2bf(v.w);
  *reinterpret_cast<ushort4*>(&hi[i]) = h;
}

// ---------------- fused weight prep: convert Wq/Wk/Wv, split Wo ----------------
__global__ __launch_bounds__(256) void prep_weights(const float* __restrict__ Wq,
                                                    const float* __restrict__ Wk,
                                                    const float* __restrict__ Wv,
                                                    const float* __restrict__ Wo,
                                                    ushort* __restrict__ Wqh,
                                                    ushort* __restrict__ Wkh,
                                                    ushort* __restrict__ Wvh,
                                                    ushort* __restrict__ Woh,
                                                    ushort* __restrict__ Wol) {
  int i = (blockIdx.x * 256 + threadIdx.x) * 4;
  int which = blockIdx.y;
  if (which == 3) {
    float4 v = *reinterpret_cast<const float4*>(&Wo[i]);
    ushort4 h, l;
    splitf(v.x, h.x, l.x);
    splitf(v.y, h.y, l.y);
    splitf(v.z, h.z, l.z);
    splitf(v.w, h.w, l.w);
    *reinterpret_cast<ushort4*>(&Woh[i]) = h;
    *reinterpret_cast<ushort4*>(&Wol[i]) = l;
  } else {
    const float* src = (which == 0) ? Wq : (which == 1) ? Wk : Wv;
    ushort* dst = (which == 0) ? Wqh : (which == 1) ? Wkh : Wvh;
    float4 v = *reinterpret_cast<const float4*>(&src[i]);
    ushort4 h;
    h.x = f2bf(v.x); h.y = f2bf(v.y); h.z = f2bf(v.z); h.w = f2bf(v.w);
    *reinterpret_cast<ushort4*>(&dst[i]) = h;
  }
}

// ---------------- 1-term bf16 GEMM: C = Ah * Bh^T ----------------
__global__ __launch_bounds__(256) void gemm1(const ushort* __restrict__ Ah_,
                                             const ushort* __restrict__ Bh_,
                                             ushort* __restrict__ Cout,
                                             int M, int N, int K) {
  __shared__ __align__(16) ushort sAh[128 * 32], sBh[128 * 32];
  const int tid = threadIdx.x;
  const int wave = tid >> 6, lane = tid & 63;
  const int lg = lane >> 4, lm = lane & 15;
  const int nwg = gridDim.x * gridDim.y;
  const int id = blockIdx.y * gridDim.x + blockIdx.x;
  const int cpx = nwg >> 3;
  const int swz = (id & 7) * cpx + (id >> 3);
  const int nbx = N >> 7;
  const int m0 = (swz / nbx) * 128, n0 = (swz % nbx) * 128;
  const int wm = (wave >> 1) * 64, wn = (wave & 1) * 64;
  f32x4 acc[4][4] = {};

  for (int k0 = 0; k0 < K; k0 += 32) {
    __syncthreads();
#pragma unroll
    for (int t = 0; t < 2; ++t) {
      int r = wave * 32 + t * 16 + (lane >> 2);
      int ca = (lane & 3) ^ ((r >> 1) & 3);
      size_t ga = (size_t)(m0 + r) * K + k0 + ca * 8;
      size_t gb = (size_t)(n0 + r) * K + k0 + ca * 8;
      int lb = (wave * 32 + t * 16) * 32;
      gload16(&Ah_[ga], &sAh[lb]);
      gload16(&Bh_[gb], &sBh[lb]);
    }
    __syncthreads();
    bf16x8 ah[4], bh[4];
#pragma unroll
    for (int t = 0; t < 4; ++t) {
      int Ra = wm + t * 16 + lm;
      int Rb = wn + t * 16 + lm;
      int ca = (lg ^ ((Ra >> 1) & 3)) * 8;
      int cb = (lg ^ ((Rb >> 1) & 3)) * 8;
      ah[t] = *reinterpret_cast<const bf16x8*>(&sAh[Ra * 32 + ca]);
      bh[t] = *reinterpret_cast<const bf16x8*>(&sBh[Rb * 32 + cb]);
    }
#pragma unroll
    for (int mi = 0; mi < 4; ++mi)
#pragma unroll
      for (int ni = 0; ni < 4; ++ni)
        acc[mi][ni] = __builtin_amdgcn_mfma_f32_16x16x32_bf16(ah[mi], bh[ni], acc[mi][ni], 0, 0, 0);
  }
#pragma unroll
  for (int mi = 0; mi < 4; ++mi)
#pragma unroll
    for (int ni = 0; ni < 4; ++ni)
#pragma unroll
      for (int j = 0; j < 4; ++j) {
        int row = m0 + wm + mi * 16 + lg * 4 + j;
        int col = n0 + wn + ni * 16 + lm;
        Cout[(size_t)row * N + col] = f2bf(acc[mi][ni][j]);
      }
}

// ---------------- 3-term bf16 GEMM (Wo, f32 out) ----------------
__global__ __launch_bounds__(256) void gemm3(const ushort* __restrict__ Ah_,
                                             const ushort* __restrict__ Al_,
                                             const ushort* __restrict__ Bh_,
                                             const ushort* __restrict__ Bl_,
                                             float* __restrict__ Cout,
                                             int M, int N, int K) {
  __shared__ __align__(16) ushort sAh[128 * 32], sAl[128 * 32], sBh[128 * 32], sBl[128 * 32];
  const int tid = threadIdx.x;
  const int wave = tid >> 6, lane = tid & 63;
  const int lg = lane >> 4, lm = lane & 15;
  const int nwg = gridDim.x * gridDim.y;
  const int id = blockIdx.y * gridDim.x + blockIdx.x;
  const int cpx = nwg >> 3;
  const int swz = (id & 7) * cpx + (id >> 3);
  const int nbx = N >> 7;
  const int m0 = (swz / nbx) * 128, n0 = (swz % nbx) * 128;
  const int wm = (wave >> 1) * 64, wn = (wave & 1) * 64;
  f32x4 acc[4][4] = {};

  for (int k0 = 0; k0 < K; k0 += 32) {
    __syncthreads();
#pragma unroll
    for (int t = 0; t < 2; ++t) {
      int r = wave * 32 + t * 16 + (lane >> 2);
      int ca = (lane & 3) ^ ((r >> 1) & 3);
      size_t ga = (size_t)(m0 + r) * K + k0 + ca * 8;
      size_t gb = (size_t)(n0 + r) * K + k0 + ca * 8;
      int lb = (wave * 32 + t * 16) * 32;
      gload16(&Ah_[ga], &sAh[lb]);
      gload16(&Al_[ga], &sAl[lb]);
      gload16(&Bh_[gb], &sBh[lb]);
      gload16(&Bl_[gb], &sBl[lb]);
    }
    __syncthreads();
    bf16x8 ah[4], al[4], bh[4], bl[4];
#pragma unroll
    for (int t = 0; t < 4; ++t) {
      int Ra = wm + t * 16 + lm;
      int Rb = wn + t * 16 + lm;
      int ca = (lg ^ ((Ra >> 1) & 3)) * 8;
      int cb = (lg ^ ((Rb >> 1) & 3)) * 8;
      ah[t] = *reinterpret_cast<const bf16x8*>(&sAh[Ra * 32 + ca]);
      al[t] = *reinterpret_cast<const bf16x8*>(&sAl[Ra * 32 + ca]);
      bh[t] = *reinterpret_cast<const bf16x8*>(&sBh[Rb * 32 + cb]);
      bl[t] = *reinterpret_cast<const bf16x8*>(&sBl[Rb * 32 + cb]);
    }
#pragma unroll
    for (int mi = 0; mi < 4; ++mi)
#pragma unroll
      for (int ni = 0; ni < 4; ++ni) {
        acc[mi][ni] = __builtin_amdgcn_mfma_f32_16x16x32_bf16(ah[mi], bh[ni], acc[mi][ni], 0, 0, 0);
        acc[mi][ni] = __builtin_amdgcn_mfma_f32_16x16x32_bf16(ah[mi], bl[ni], acc[mi][ni], 0, 0, 0);
        acc[mi][ni] = __builtin_amdgcn_mfma_f32_16x16x32_bf16(al[mi], bh[ni], acc[mi][ni], 0, 0, 0);
      }
  }
#pragma unroll
  for (int mi = 0; mi < 4; ++mi)
#pragma unroll
    for (int ni = 0; ni < 4; ++ni)
#pragma unroll
      for (int j = 0; j < 4; ++j) {
        int row = m0 + wm + mi * 16 + lg * 4 + j;
        int col = n0 + wn + ni * 16 + lm;
        Cout[(size_t)row * N + col] = acc[mi][ni][j];
      }
}

// ---------------- RoPE in-place: Q scaled by log2e/sqrt(HD) (exp2-domain softmax) ----------------
__global__ __launch_bounds__(256) void rope2_kernel(ushort* __restrict__ Q,
                                                    ushort* __restrict__ K,
                                                    const int* __restrict__ pos,
                                                    const float* __restrict__ cosT,
                                                    const float* __restrict__ sinT) {
  int idx = blockIdx.x * 256 + threadIdx.x;
  int s = idx >> 10, dh = idx & 1023;
  int hh = dh >> 6, j = dh & 63;
  int p = pos[s];
  float cs = cosT[p * 64 + j], sn = sinT[p * 64 + j];
  size_t i1 = (size_t)s * DMODEL + hh * HEADDIM + j, i2 = i1 + 64;
  float q1 = bf2f(Q[i1]), q2 = bf2f(Q[i2]);
  float k1 = bf2f(K[i1]), k2 = bf2f(K[i2]);
  const float scl = 0.12751742f;  // log2(e)/sqrt(128)
  Q[i1] = f2bf((q1 * cs - q2 * sn) * scl);
  Q[i2] = f2bf((q2 * cs + q1 * sn) * scl);
  K[i1] = f2bf(k1 * cs - k2 * sn);
  K[i2] = f2bf(k2 * cs + k1 * sn);
}

// ---------------- V transpose ----------------
__global__ __launch_bounds__(256) void transpose_kernel(const ushort* __restrict__ Vr,
                                                        ushort* __restrict__ Vt) {
  __shared__ __align__(16) ushort tile[64 * 72];
  int tid = threadIdx.x;
  int s0 = blockIdx.x * 64, c0 = blockIdx.y * 64;
#pragma unroll
  for (int it = 0; it < 2; ++it) {
    int i = tid + it * 256;
    int r = i >> 3, c = i & 7;
    *reinterpret_cast<uint4*>(&tile[r * 72 + c * 8]) =
        *reinterpret_cast<const uint4*>(&Vr[(size_t)(s0 + r) * DMODEL + c0 + c * 8]);
  }
  __syncthreads();
#pragma unroll
  for (int it = 0; it < 2; ++it) {
    int i = tid + it * 256;
    int cr = i >> 3, sc = i & 7;
    ushort tmp[8];
#pragma unroll
    for (int j = 0; j < 8; ++j) tmp[j] = tile[(sc * 8 + j) * 72 + cr];
    *reinterpret_cast<uint4*>(&Vt[(size_t)(c0 + cr) * S_LEN + s0 + sc * 8]) =
        *reinterpret_cast<uint4*>(tmp);
  }
}

// ---------------- Flash attention v9 ----------------
// 4 waves x 32 q-rows, QBLK=128, KBLK=64, 2 blocks/CU.
// K staged in LDS (rho-permuted, XOR-swizzled, double-buffered as TWO DISTINCT
// __shared__ arrays referenced statically -> no alias-forced waits).
// V read DIRECTLY global->registers (L2-resident per head), prefetched in two
// halves so latency hides under QK^T / softmax. exp2-domain softmax.
#define FLASH_BODY(KCUR, KNXT, T, STAGE_NEXT)                                              \
  {                                                                                        \
    const int t_ = (T);                                                                    \
    /* V prefetch: first half (nb 0..3) */                                                 \
    bf16x8 vrA[4][2], vrB[4][2];                                                           \
    const size_t vco = (size_t)t_ * 64;                                                    \
    _Pragma("unroll") for (int nb = 0; nb < 4; ++nb)                                       \
        _Pragma("unroll") for (int kk = 0; kk < 2; ++kk)                                   \
            vrA[nb][kk] = *reinterpret_cast<const bf16x8*>(                                \
                &Vt[(size_t)(h * HEADDIM + nb * 16 + lm) * S_LEN + vco + kk * 32 + lg * 8]); \
    if (STAGE_NEXT) {                                                                      \
      const size_t koff = (size_t)(t_ + 1) * 64 * DMODEL;                                  \
      _Pragma("unroll") for (int k = 0; k < 4; ++k)                                        \
          gload16(pK[k] + koff, &KNXT[lbs[k]]);                                            \
    }                                                                                      \
    /* QK^T swapped */                                                                     \
    f32x4 st[2][4] = {};                                                                   \
    __builtin_amdgcn_s_setprio(1);                                                         \
    _Pragma("unroll") for (int nf = 0; nf < 4; ++nf)                                       \
        _Pragma("unroll") for (int kc = 0; kc < 4; ++kc) {                                 \
      int pc = (kc * 4 + lg) ^ (lm & 7);                                                   \
      bf16x8 kfrag = *reinterpret_cast<const bf16x8*>(&KCUR[(nf * 16 + lm) * 128 + pc * 8]); \
      st[0][nf] = __builtin_amdgcn_mfma_f32_16x16x32_bf16(kfrag, qh[0][kc], st[0][nf], 0, 0, 0); \
      st[1][nf] = __builtin_amdgcn_mfma_f32_16x16x32_bf16(kfrag, qh[1][kc], st[1][nf], 0, 0, 0); \
    }                                                                                      \
    __builtin_amdgcn_s_setprio(0);                                                         \
    /* V prefetch: second half (nb 4..7) */                                                \
    _Pragma("unroll") for (int nb = 0; nb < 4; ++nb)                                       \
        _Pragma("unroll") for (int kk = 0; kk < 2; ++kk)                                   \
            vrB[nb][kk] = *reinterpret_cast<const bf16x8*>(                                \
                &Vt[(size_t)(h * HEADDIM + (nb + 4) * 16 + lm) * S_LEN + vco + kk * 32 + lg * 8]); \
    /* row max */                                                                          \
    float m16[2];                                                                          \
    _Pragma("unroll") for (int t2 = 0; t2 < 2; ++t2) {                                     \
      float m = fmaxf(st[t2][0][0], st[t2][0][1]);                                         \
      m = fmaxf(fmaxf(m, st[t2][0][2]), st[t2][0][3]);                                     \
      m = fmaxf(fmaxf(m, st[t2][1][0]), st[t2][1][1]);                                     \
      m = fmaxf(fmaxf(m, st[t2][1][2]), st[t2][1][3]);                                     \
      m = fmaxf(fmaxf(m, st[t2][2][0]), st[t2][2][1]);                                     \
      m = fmaxf(fmaxf(m, st[t2][2][2]), st[t2][2][3]);                                     \
      m = fmaxf(fmaxf(m, st[t2][3][0]), st[t2][3][1]);                                     \
      m = fmaxf(fmaxf(m, st[t2][3][2]), st[t2][3][3]);                                     \
      m = fmaxf(m, __shfl_xor(m, 16));                                                     \
      m = fmaxf(m, __shfl_xor(m, 32));                                                     \
      m16[t2] = m;                                                                         \
    }                                                                                      \
    /* defer-max rescale (exp2 domain, thr 11.5 = 8*log2e) */                              \
    bool grow = (m16[0] > mrun[0] + 11.5f) || (m16[1] > mrun[1] + 11.5f);                  \
    if (__any(grow)) {                                                                     \
      _Pragma("unroll") for (int t2 = 0; t2 < 2; ++t2) {                                   \
        float mn = fmaxf(mrun[t2], m16[t2]);                                               \
        float scl = exp2f(mrun[t2] - mn);                                                  \
        mrun[t2] = mn;                                                                     \
        float sj[4];                                                                       \
        _Pragma("unroll") for (int j = 0; j < 4; ++j) sj[j] = __shfl(scl, lg * 4 + j);     \
        _Pragma("unroll") for (int j = 0; j < 4; ++j) osum[t2][j] *= sj[j];                \
        _Pragma("unroll") for (int nb = 0; nb < 8; ++nb)                                   \
            _Pragma("unroll") for (int j = 0; j < 4; ++j) oacc[t2][nb][j] *= sj[j];        \
      }                                                                                    \
    }                                                                                      \
    /* P = exp2(S2 - m2) */                                                                \
    _Pragma("unroll") for (int t2 = 0; t2 < 2; ++t2)                                       \
        _Pragma("unroll") for (int nf = 0; nf < 4; ++nf)                                   \
            _Pragma("unroll") for (int j = 0; j < 4; ++j)                                  \
                st[t2][nf][j] = exp2f(st[t2][nf][j] - mrun[t2]);                           \
    /* pack PV A-frags */                                                                  \
    bf16x8 pa[2][2];                                                                       \
    _Pragma("unroll") for (int t2 = 0; t2 < 2; ++t2)                                       \
        _Pragma("unroll") for (int kk = 0; kk < 2; ++kk) {                                 \
      union { unsigned int u[4]; bf16x8 v; } w_;                                           \
      w_.u[0] = cvtpk(st[t2][kk][0], st[t2][kk][1]);                                       \
      w_.u[1] = cvtpk(st[t2][kk][2], st[t2][kk][3]);                                       \
      w_.u[2] = cvtpk(st[t2][2 + kk][0], st[t2][2 + kk][1]);                               \
      w_.u[3] = cvtpk(st[t2][2 + kk][2], st[t2][2 + kk][3]);                               \
      pa[t2][kk] = w_.v;                                                                   \
    }                                                                                      \
    /* PV + row-sum via ones-MFMA */                                                       \
    __builtin_amdgcn_s_setprio(1);                                                         \
    _Pragma("unroll") for (int t2 = 0; t2 < 2; ++t2) {                                     \
      osum[t2] = __builtin_amdgcn_mfma_f32_16x16x32_bf16(pa[t2][0], ones, osum[t2], 0, 0, 0); \
      osum[t2] = __builtin_amdgcn_mfma_f32_16x16x32_bf16(pa[t2][1], ones, osum[t2], 0, 0, 0); \
    }                                                                                      \
    _Pragma("unroll") for (int nb = 0; nb < 4; ++nb)                                       \
        _Pragma("unroll") for (int kk = 0; kk < 2; ++kk) {                                 \
      oacc[0][nb] = __builtin_amdgcn_mfma_f32_16x16x32_bf16(pa[0][kk], vrA[nb][kk], oacc[0][nb], 0, 0, 0); \
      oacc[1][nb] = __builtin_amdgcn_mfma_f32_16x16x32_bf16(pa[1][kk], vrA[nb][kk], oacc[1][nb], 0, 0, 0); \
    }                                                                                      \
    _Pragma("unroll") for (int nb = 0; nb < 4; ++nb)                                       \
        _Pragma("unroll") for (int kk = 0; kk < 2; ++kk) {                                 \
      oacc[0][nb + 4] = __builtin_amdgcn_mfma_f32_16x16x32_bf16(pa[0][kk], vrB[nb][kk], oacc[0][nb + 4], 0, 0, 0); \
      oacc[1][nb + 4] = __builtin_amdgcn_mfma_f32_16x16x32_bf16(pa[1][kk], vrB[nb][kk], oacc[1][nb + 4], 0, 0, 0); \
    }                                                                                      \
    __builtin_amdgcn_s_setprio(0);                                                         \
    __syncthreads();                                                                       \
  }

__global__ __launch_bounds__(256, 2) void flash9_kernel(const ushort* __restrict__ Q,
                                                        const ushort* __restrict__ Kb,
                                                        const ushort* __restrict__ Vt,
                                                        ushort* __restrict__ Oh,
                                                        ushort* __restrict__ Ol) {
  __shared__ __align__(16) ushort KtA[64 * 128];
  __shared__ __align__(16) ushort KtB[64 * 128];
  const int tid = threadIdx.x;             // 0..255
  const int wave = tid >> 6, lane = tid & 63;
  const int lg = lane >> 4, lm = lane & 15;
  const int id = blockIdx.y * gridDim.x + blockIdx.x;  // 0..511
  const int o = (id & 7) * 64 + (id >> 3);             // XCD swizzle (512 = 8*64)
  const int h = o >> 5;
  const int q0 = (o & 31) * 128;

  bf16x8 qh[2][4];
#pragma unroll
  for (int t2 = 0; t2 < 2; ++t2) {
    int qrow = q0 + wave * 32 + t2 * 16 + lm;
#pragma unroll
    for (int kc = 0; kc < 4; ++kc)
      qh[t2][kc] = *reinterpret_cast<const bf16x8*>(
          &Q[(size_t)qrow * DMODEL + h * HEADDIM + kc * 32 + lg * 8]);
  }

  bf16x8 ones;
#pragma unroll
  for (int i = 0; i < 8; ++i) ones[i] = (short)0x3f80;  // bf16 1.0

  // K staging: 1024 chunks, 256 threads -> 4 each; rho-permuted source rows,
  // XOR-swizzled source chunk so linear LDS + swizzled read works (rule #21)
  auto rho = [](int s) {
    return 32 * ((s >> 4) & 1) + 8 * ((s >> 2) & 3) + 4 * (s >> 5) + (s & 3);
  };
  const ushort* pK[4];
  int lbs[4];
#pragma unroll
  for (int k = 0; k < 4; ++k) {
    int ci = k * 256 + wave * 64 + lane;
    int ks = ci >> 4;
    int kcc = (ci & 15) ^ (ks & 7);
    pK[k] = Kb + (size_t)rho(ks) * DMODEL + h * HEADDIM + kcc * 8;
    lbs[k] = (k * 256 + wave * 64) * 8;
  }

  f32x4 oacc[2][8] = {};
  f32x4 osum[2] = {};
  float mrun[2];
#pragma unroll
  for (int t2 = 0; t2 < 2; ++t2) mrun[t2] = -3.0e38f;

  // prologue: stage tile 0 -> KtA
#pragma unroll
  for (int k = 0; k < 4; ++k) gload16(pK[k], &KtA[lbs[k]]);
  __syncthreads();

  for (int tp = 0; tp < S_LEN / 128; ++tp) {
    const int t0 = 2 * tp;
    FLASH_BODY(KtA, KtB, t0, true)
    FLASH_BODY(KtB, KtA, t0 + 1, (t0 + 1 < S_LEN / 64 - 1))
  }

  // epilogue
#pragma unroll
  for (int t2 = 0; t2 < 2; ++t2) {
    float linv[4];
#pragma unroll
    for (int j = 0; j < 4; ++j) linv[j] = 1.0f / osum[t2][j];
#pragma unroll
    for (int nb = 0; nb < 8; ++nb)
#pragma unroll
      for (int j = 0; j < 4; ++j) {
        int row = q0 + wave * 32 + t2 * 16 + lg * 4 + j;
        int col = h * HEADDIM + nb * 16 + lm;
        float ov = oacc[t2][nb][j] * linv[j];
        ushort hi, lo;
        splitf(ov, hi, lo);
        Oh[(size_t)row * DMODEL + col] = hi;
        Ol[(size_t)row * DMODEL + col] = lo;
      }
  }
}

extern "C" void kernel_launch(void* const* d_in, const int* in_sizes, int n_in,
                              void* d_out, int out_size, void* d_ws, size_t ws_size,
                              hipStream_t stream) {
  (void)in_sizes; (void)n_in; (void)out_size; (void)ws_size;
  const float* X  = (const float*)d_in[0];
  const float* Wq = (const float*)d_in[1];
  const float* Wk = (const float*)d_in[2];
  const float* Wv = (const float*)d_in[3];
  const float* Wo = (const float*)d_in[4];
  const int* pos  = (const int*)d_in[5];
  float* out = (float*)d_out;

  ushort* wb = (ushort*)d_ws;
  const size_t SD = (size_t)S_LEN * DMODEL;       // 8388608 elements
  const size_t DD = (size_t)DMODEL * DMODEL;      // 4194304 elements

  ushort* Xh  = wb;              // slot0
  ushort* OlB = wb + SD;         // slot1 (free until flash)
  ushort* Qr  = wb + 2 * SD;     // slot2
  ushort* Kr  = wb + 3 * SD;     // slot3
  ushort* Vr  = wb + 4 * SD;     // slot4: later Oh
  ushort* Vt  = wb + 5 * SD;     // slot5
  ushort* W0h = wb + 6 * SD;     // Wo hi
  ushort* W0l = wb + 6 * SD + DD;  // Wo lo
  ushort* Wqh = wb + 7 * SD;
  ushort* Wkh = wb + 7 * SD + DD;
  ushort* Wvh = wb + 8 * SD;
  float* cosT = (float*)(wb + 9 * SD);
  float* sinT = cosT + (size_t)S_LEN * 64;
  ushort* OhB = Vr;  // reuse after transpose

  rope_table_kernel<<<S_LEN * 64 / 256, 256, 0, stream>>>(cosT, sinT);
  convert_kernel<<<SD / 1024, 256, 0, stream>>>(X, Xh);
  prep_weights<<<dim3(DD / 1024, 4), 256, 0, stream>>>(Wq, Wk, Wv, Wo, Wqh, Wkh, Wvh, W0h, W0l);

  dim3 gemmGrid(DMODEL / 128, S_LEN / 128);
  gemm1<<<gemmGrid, 256, 0, stream>>>(Xh, Wqh, Qr, S_LEN, DMODEL, DMODEL);
  gemm1<<<gemmGrid, 256, 0, stream>>>(Xh, Wkh, Kr, S_LEN, DMODEL, DMODEL);
  gemm1<<<gemmGrid, 256, 0, stream>>>(Xh, Wvh, Vr, S_LEN, DMODEL, DMODEL);

  rope2_kernel<<<(S_LEN * 1024) / 256, 256, 0, stream>>>(Qr, Kr, pos, cosT, sinT);
  transpose_kernel<<<dim3(S_LEN / 64, DMODEL / 64), 256, 0, stream>>>(Vr, Vt);

  flash9_kernel<<<dim3(32, 16), 256, 0, stream>>>(Qr, Kr, Vt, OhB, OlB);

  gemm3<<<gemmGrid, 256, 0, stream>>>(OhB, OlB, W0h, W0l, out, S_LEN, DMODEL, DMODEL);
}

// Round 9
// 429.443 us; speedup vs baseline: 1.4990x; 1.4990x over previous
//
#include <hip/hip_runtime.h>
#include <hip/hip_bf16.h>

#define S_LEN 4096
#define DMODEL 2048
#define NHEADS 16
#define HEADDIM 128
#define LDQ 6144  // stride of fused QKV buffer

typedef __attribute__((ext_vector_type(8))) short bf16x8;
typedef __attribute__((ext_vector_type(4))) float f32x4;

__device__ __forceinline__ float bf2f(ushort u) {
  union { unsigned int i; float f; } x; x.i = ((unsigned int)u) << 16; return x.f;
}
__device__ __forceinline__ ushort f2bf(float f) {
  union { float f; unsigned int i; } x; x.f = f;
  unsigned int u = x.i;
  unsigned int r = u + 0x7fffu + ((u >> 16) & 1u);
  return (ushort)(r >> 16);
}
__device__ __forceinline__ void splitf(float f, ushort& h, ushort& l) {
  unsigned int u = __float_as_uint(f);
  h = (ushort)(u >> 16);
  l = f2bf(f - __uint_as_float(u & 0xffff0000u));
}
__device__ __forceinline__ unsigned int cvtpk(float a, float b) {
  unsigned int r;
  asm("v_cvt_pk_bf16_f32 %0, %1, %2" : "=v"(r) : "v"(a), "v"(b));
  return r;
}

__device__ __forceinline__ void gload16(const ushort* g, ushort* l) {
  __builtin_amdgcn_global_load_lds(
      (const __attribute__((address_space(1))) unsigned int*)g,
      (__attribute__((address_space(3))) unsigned int*)l, 16, 0, 0);
}

// ---------------- RoPE cos/sin table ----------------
__global__ __launch_bounds__(256) void rope_table_kernel(float* __restrict__ cosT,
                                                         float* __restrict__ sinT) {
  int idx = blockIdx.x * 256 + threadIdx.x;
  int t = idx >> 6, j = idx & 63;
  float expo = (float)(2 * j) / 128.0f;
  float inv = 1.0f / powf(10000.0f, expo);
  float f = (float)t * inv;
  cosT[idx] = cosf(f);
  sinT[idx] = sinf(f);
}

// ---------------- fp32 -> bf16 (RNE) convert ----------------
__global__ __launch_bounds__(256) void convert_kernel(const float* __restrict__ in,
                                                      ushort* __restrict__ hi) {
  int i = (blockIdx.x * 256 + threadIdx.x) * 4;
  float4 v = *reinterpret_cast<const float4*>(&in[i]);
  ushort4 h;
  h.x = f2bf(v.x); h.y = f2bf(v.y); h.z = f2bf(v.z); h.w = f2bf(v.w);
  *reinterpret_cast<ushort4*>(&hi[i]) = h;
}

// ---------------- fused weight prep: Wq/Wk/Wv -> packed bf16 [6144][2048]; Wo -> hi/lo ----------------
__global__ __launch_bounds__(256) void prep_weights(const float* __restrict__ Wq,
                                                    const float* __restrict__ Wk,
                                                    const float* __restrict__ Wv,
                                                    const float* __restrict__ Wo,
                                                    ushort* __restrict__ Wqkv,
                                                    ushort* __restrict__ Woh,
                                                    ushort* __restrict__ Wol) {
  int i = (blockIdx.x * 256 + threadIdx.x) * 4;
  int which = blockIdx.y;
  if (which == 3) {
    float4 v = *reinterpret_cast<const float4*>(&Wo[i]);
    ushort4 h, l;
    splitf(v.x, h.x, l.x);
    splitf(v.y, h.y, l.y);
    splitf(v.z, h.z, l.z);
    splitf(v.w, h.w, l.w);
    *reinterpret_cast<ushort4*>(&Woh[i]) = h;
    *reinterpret_cast<ushort4*>(&Wol[i]) = l;
  } else {
    const float* src = (which == 0) ? Wq : (which == 1) ? Wk : Wv;
    float4 v = *reinterpret_cast<const float4*>(&src[i]);
    ushort4 h;
    h.x = f2bf(v.x); h.y = f2bf(v.y); h.z = f2bf(v.z); h.w = f2bf(v.w);
    *reinterpret_cast<ushort4*>(&Wqkv[(size_t)which * DMODEL * DMODEL + i]) = h;
  }
}

// ---------------- fused QKV GEMM: QKV = Xh * Wqkv^T, BK=64, 128x128 tile ----------------
// A [4096][2048] bf16, B [6144][2048] bf16, C [4096][6144] bf16.
// LDS [128][64] linear per array; XOR swizzle pc = cc ^ (row&7) on both sides (rule #21).
__global__ __launch_bounds__(256) void gemm_qkv(const ushort* __restrict__ Ah_,
                                                const ushort* __restrict__ Bh_,
                                                ushort* __restrict__ Cout,
                                                int M, int N, int K) {
  __shared__ __align__(16) ushort sAh[128 * 64], sBh[128 * 64];
  const int tid = threadIdx.x;
  const int wave = tid >> 6, lane = tid & 63;
  const int lg = lane >> 4, lm = lane & 15;
  const int nwg = gridDim.x * gridDim.y;
  const int id = blockIdx.y * gridDim.x + blockIdx.x;
  const int cpx = nwg >> 3;
  const int swz = (id & 7) * cpx + (id >> 3);
  const int nbx = N >> 7;
  const int m0 = (swz / nbx) * 128, n0 = (swz % nbx) * 128;
  const int wm = (wave >> 1) * 64, wn = (wave & 1) * 64;
  f32x4 acc[4][4] = {};

  // staging geometry: 1024 chunks per array, 4 per thread
  int srow[4], scc[4], lbs[4];
#pragma unroll
  for (int it = 0; it < 4; ++it) {
    int ci = it * 256 + wave * 64 + lane;
    srow[it] = ci >> 3;
    scc[it] = (ci & 7) ^ (srow[it] & 7);
    lbs[it] = (it * 256 + wave * 64) * 8;
  }

  for (int k0 = 0; k0 < K; k0 += 64) {
    __syncthreads();
#pragma unroll
    for (int it = 0; it < 4; ++it) {
      size_t ga = (size_t)(m0 + srow[it]) * K + k0 + scc[it] * 8;
      size_t gb = (size_t)(n0 + srow[it]) * K + k0 + scc[it] * 8;
      gload16(&Ah_[ga], &sAh[lbs[it]]);
      gload16(&Bh_[gb], &sBh[lbs[it]]);
    }
    __syncthreads();
    bf16x8 ah[4][2], bh[4][2];
#pragma unroll
    for (int t = 0; t < 4; ++t)
#pragma unroll
      for (int kc = 0; kc < 2; ++kc) {
        int Ra = wm + t * 16 + lm;
        int Rb = wn + t * 16 + lm;
        int pa_ = ((kc * 4 + lg) ^ (Ra & 7)) * 8;
        int pb_ = ((kc * 4 + lg) ^ (Rb & 7)) * 8;
        ah[t][kc] = *reinterpret_cast<const bf16x8*>(&sAh[Ra * 64 + pa_]);
        bh[t][kc] = *reinterpret_cast<const bf16x8*>(&sBh[Rb * 64 + pb_]);
      }
#pragma unroll
    for (int kc = 0; kc < 2; ++kc)
#pragma unroll
      for (int mi = 0; mi < 4; ++mi)
#pragma unroll
        for (int ni = 0; ni < 4; ++ni)
          acc[mi][ni] = __builtin_amdgcn_mfma_f32_16x16x32_bf16(ah[mi][kc], bh[ni][kc], acc[mi][ni], 0, 0, 0);
  }
#pragma unroll
  for (int mi = 0; mi < 4; ++mi)
#pragma unroll
    for (int ni = 0; ni < 4; ++ni)
#pragma unroll
      for (int j = 0; j < 4; ++j) {
        int row = m0 + wm + mi * 16 + lg * 4 + j;
        int col = n0 + wn + ni * 16 + lm;
        Cout[(size_t)row * N + col] = f2bf(acc[mi][ni][j]);
      }
}

// ---------------- 3-term bf16 GEMM (Wo, f32 out) ----------------
__global__ __launch_bounds__(256) void gemm3(const ushort* __restrict__ Ah_,
                                             const ushort* __restrict__ Al_,
                                             const ushort* __restrict__ Bh_,
                                             const ushort* __restrict__ Bl_,
                                             float* __restrict__ Cout,
                                             int M, int N, int K) {
  __shared__ __align__(16) ushort sAh[128 * 32], sAl[128 * 32], sBh[128 * 32], sBl[128 * 32];
  const int tid = threadIdx.x;
  const int wave = tid >> 6, lane = tid & 63;
  const int lg = lane >> 4, lm = lane & 15;
  const int nwg = gridDim.x * gridDim.y;
  const int id = blockIdx.y * gridDim.x + blockIdx.x;
  const int cpx = nwg >> 3;
  const int swz = (id & 7) * cpx + (id >> 3);
  const int nbx = N >> 7;
  const int m0 = (swz / nbx) * 128, n0 = (swz % nbx) * 128;
  const int wm = (wave >> 1) * 64, wn = (wave & 1) * 64;
  f32x4 acc[4][4] = {};

  for (int k0 = 0; k0 < K; k0 += 32) {
    __syncthreads();
#pragma unroll
    for (int t = 0; t < 2; ++t) {
      int r = wave * 32 + t * 16 + (lane >> 2);
      int ca = (lane & 3) ^ ((r >> 1) & 3);
      size_t ga = (size_t)(m0 + r) * K + k0 + ca * 8;
      size_t gb = (size_t)(n0 + r) * K + k0 + ca * 8;
      int lb = (wave * 32 + t * 16) * 32;
      gload16(&Ah_[ga], &sAh[lb]);
      gload16(&Al_[ga], &sAl[lb]);
      gload16(&Bh_[gb], &sBh[lb]);
      gload16(&Bl_[gb], &sBl[lb]);
    }
    __syncthreads();
    bf16x8 ah[4], al[4], bh[4], bl[4];
#pragma unroll
    for (int t = 0; t < 4; ++t) {
      int Ra = wm + t * 16 + lm;
      int Rb = wn + t * 16 + lm;
      int ca = (lg ^ ((Ra >> 1) & 3)) * 8;
      int cb = (lg ^ ((Rb >> 1) & 3)) * 8;
      ah[t] = *reinterpret_cast<const bf16x8*>(&sAh[Ra * 32 + ca]);
      al[t] = *reinterpret_cast<const bf16x8*>(&sAl[Ra * 32 + ca]);
      bh[t] = *reinterpret_cast<const bf16x8*>(&sBh[Rb * 32 + cb]);
      bl[t] = *reinterpret_cast<const bf16x8*>(&sBl[Rb * 32 + cb]);
    }
#pragma unroll
    for (int mi = 0; mi < 4; ++mi)
#pragma unroll
      for (int ni = 0; ni < 4; ++ni) {
        acc[mi][ni] = __builtin_amdgcn_mfma_f32_16x16x32_bf16(ah[mi], bh[ni], acc[mi][ni], 0, 0, 0);
        acc[mi][ni] = __builtin_amdgcn_mfma_f32_16x16x32_bf16(ah[mi], bl[ni], acc[mi][ni], 0, 0, 0);
        acc[mi][ni] = __builtin_amdgcn_mfma_f32_16x16x32_bf16(al[mi], bh[ni], acc[mi][ni], 0, 0, 0);
      }
  }
#pragma unroll
  for (int mi = 0; mi < 4; ++mi)
#pragma unroll
    for (int ni = 0; ni < 4; ++ni)
#pragma unroll
      for (int j = 0; j < 4; ++j) {
        int row = m0 + wm + mi * 16 + lg * 4 + j;
        int col = n0 + wn + ni * 16 + lm;
        Cout[(size_t)row * N + col] = acc[mi][ni][j];
      }
}

// ---------------- RoPE in-place on QKV buffer: Q scaled by log2e/sqrt(HD) ----------------
__global__ __launch_bounds__(256) void rope2_kernel(ushort* __restrict__ QKV,
                                                    const int* __restrict__ pos,
                                                    const float* __restrict__ cosT,
                                                    const float* __restrict__ sinT) {
  int idx = blockIdx.x * 256 + threadIdx.x;
  int s = idx >> 10, dh = idx & 1023;
  int hh = dh >> 6, j = dh & 63;
  int p = pos[s];
  float cs = cosT[p * 64 + j], sn = sinT[p * 64 + j];
  size_t i1 = (size_t)s * LDQ + hh * HEADDIM + j, i2 = i1 + 64;
  size_t k1i = i1 + DMODEL, k2i = i2 + DMODEL;
  float q1 = bf2f(QKV[i1]), q2 = bf2f(QKV[i2]);
  float k1 = bf2f(QKV[k1i]), k2 = bf2f(QKV[k2i]);
  const float scl = 0.12751742f;  // log2(e)/sqrt(128)
  QKV[i1] = f2bf((q1 * cs - q2 * sn) * scl);
  QKV[i2] = f2bf((q2 * cs + q1 * sn) * scl);
  QKV[k1i] = f2bf(k1 * cs - k2 * sn);
  QKV[k2i] = f2bf(k2 * cs + k1 * sn);
}

// ---------------- V transpose: QKV V-columns [S][2048 @ off 4096, ld 6144] -> Vt [2048][S] ----------------
__global__ __launch_bounds__(256) void transpose_kernel(const ushort* __restrict__ Vr,
                                                        ushort* __restrict__ Vt) {
  __shared__ __align__(16) ushort tile[64 * 72];
  int tid = threadIdx.x;
  int s0 = blockIdx.x * 64, c0 = blockIdx.y * 64;
#pragma unroll
  for (int it = 0; it < 2; ++it) {
    int i = tid + it * 256;
    int r = i >> 3, c = i & 7;
    *reinterpret_cast<uint4*>(&tile[r * 72 + c * 8]) =
        *reinterpret_cast<const uint4*>(&Vr[(size_t)(s0 + r) * LDQ + c0 + c * 8]);
  }
  __syncthreads();
#pragma unroll
  for (int it = 0; it < 2; ++it) {
    int i = tid + it * 256;
    int cr = i >> 3, sc = i & 7;
    ushort tmp[8];
#pragma unroll
    for (int j = 0; j < 8; ++j) tmp[j] = tile[(sc * 8 + j) * 72 + cr];
    *reinterpret_cast<uint4*>(&Vt[(size_t)(c0 + cr) * S_LEN + s0 + sc * 8]) =
        *reinterpret_cast<uint4*>(tmp);
  }
}

// ---------------- Flash attention v10 = flash7 structure (known good) on QKV buffer ----------------
// 4 waves x 32 q-rows, QBLK=128, KBLK=64, 2 blocks/CU. K+V LDS-staged (double-buffered),
// swapped QK^T + rho key permutation via per-lane gload_lds source, XOR chunk swizzle,
// exp2-domain softmax, ones-MFMA row-sum.
__global__ __launch_bounds__(256, 2) void flash10_kernel(const ushort* __restrict__ QKV,
                                                         const ushort* __restrict__ Vt,
                                                         ushort* __restrict__ Oh,
                                                         ushort* __restrict__ Ol) {
  __shared__ __align__(16) ushort Kt[2][64 * 128];
  __shared__ __align__(16) ushort Vs[2][128 * 64];
  const int tid = threadIdx.x;             // 0..255
  const int wave = tid >> 6, lane = tid & 63;
  const int lg = lane >> 4, lm = lane & 15;
  const int id = blockIdx.y * gridDim.x + blockIdx.x;  // 0..511
  const int o = (id & 7) * 64 + (id >> 3);             // XCD swizzle (512 = 8*64)
  const int h = o >> 5;
  const int q0 = (o & 31) * 128;

  bf16x8 qh[2][4];
#pragma unroll
  for (int t2 = 0; t2 < 2; ++t2) {
    int qrow = q0 + wave * 32 + t2 * 16 + lm;
#pragma unroll
    for (int kc = 0; kc < 4; ++kc)
      qh[t2][kc] = *reinterpret_cast<const bf16x8*>(
          &QKV[(size_t)qrow * LDQ + h * HEADDIM + kc * 32 + lg * 8]);
  }

  bf16x8 ones;
#pragma unroll
  for (int i = 0; i < 8; ++i) ones[i] = (short)0x3f80;  // bf16 1.0

  auto rho = [](int s) {
    return 32 * ((s >> 4) & 1) + 8 * ((s >> 2) & 3) + 4 * (s >> 5) + (s & 3);
  };
  const ushort* Kb = QKV + DMODEL;  // K columns
  const ushort* pK[4];
  const ushort* pV[4];
  int lbs[4];
#pragma unroll
  for (int k = 0; k < 4; ++k) {
    int ci = k * 256 + wave * 64 + lane;
    int ks = ci >> 4;
    int kcc = (ci & 15) ^ (ks & 7);
    pK[k] = Kb + (size_t)rho(ks) * LDQ + h * HEADDIM + kcc * 8;
    int vd = ci >> 3;
    int vcc = (ci & 7) ^ (vd & 7);
    pV[k] = Vt + (size_t)(h * HEADDIM + vd) * S_LEN + vcc * 8;
    lbs[k] = (k * 256 + wave * 64) * 8;
  }

  f32x4 oacc[2][8] = {};
  f32x4 osum[2] = {};
  float mrun[2];
#pragma unroll
  for (int t2 = 0; t2 < 2; ++t2) mrun[t2] = -3.0e38f;

#pragma unroll
  for (int k = 0; k < 4; ++k) {
    gload16(pK[k], &Kt[0][lbs[k]]);
    gload16(pV[k], &Vs[0][lbs[k]]);
  }
  __syncthreads();

  for (int t = 0; t < S_LEN / 64; ++t) {
    const int cur = t & 1;
    if (t < S_LEN / 64 - 1) {
      const size_t koff = (size_t)(t + 1) * 64;
#pragma unroll
      for (int k = 0; k < 4; ++k) {
        gload16(pK[k] + koff * LDQ, &Kt[cur ^ 1][lbs[k]]);
        gload16(pV[k] + koff, &Vs[cur ^ 1][lbs[k]]);
      }
    }
    const ushort* Kc = &Kt[cur][0];
    const ushort* Vc = &Vs[cur][0];

    // QK^T swapped
    f32x4 st[2][4] = {};
    __builtin_amdgcn_s_setprio(1);
#pragma unroll
    for (int nf = 0; nf < 4; ++nf)
#pragma unroll
      for (int kc = 0; kc < 4; ++kc) {
        int pc = (kc * 4 + lg) ^ (lm & 7);
        bf16x8 kfrag = *reinterpret_cast<const bf16x8*>(&Kc[(nf * 16 + lm) * 128 + pc * 8]);
        st[0][nf] = __builtin_amdgcn_mfma_f32_16x16x32_bf16(kfrag, qh[0][kc], st[0][nf], 0, 0, 0);
        st[1][nf] = __builtin_amdgcn_mfma_f32_16x16x32_bf16(kfrag, qh[1][kc], st[1][nf], 0, 0, 0);
      }
    __builtin_amdgcn_s_setprio(0);

    // row max: fmax tree then cross-replica reduce
    float m16[2];
#pragma unroll
    for (int t2 = 0; t2 < 2; ++t2) {
      float m = fmaxf(st[t2][0][0], st[t2][0][1]);
      m = fmaxf(fmaxf(m, st[t2][0][2]), st[t2][0][3]);
      m = fmaxf(fmaxf(m, st[t2][1][0]), st[t2][1][1]);
      m = fmaxf(fmaxf(m, st[t2][1][2]), st[t2][1][3]);
      m = fmaxf(fmaxf(m, st[t2][2][0]), st[t2][2][1]);
      m = fmaxf(fmaxf(m, st[t2][2][2]), st[t2][2][3]);
      m = fmaxf(fmaxf(m, st[t2][3][0]), st[t2][3][1]);
      m = fmaxf(fmaxf(m, st[t2][3][2]), st[t2][3][3]);
      m = fmaxf(m, __shfl_xor(m, 16));
      m = fmaxf(m, __shfl_xor(m, 32));
      m16[t2] = m;
    }

    // defer-max rescale (exp2 domain, thr 11.5 ~= 8*log2e)
    bool grow = (m16[0] > mrun[0] + 11.5f) || (m16[1] > mrun[1] + 11.5f);
    if (__any(grow)) {
#pragma unroll
      for (int t2 = 0; t2 < 2; ++t2) {
        float mn = fmaxf(mrun[t2], m16[t2]);
        float scl = exp2f(mrun[t2] - mn);
        mrun[t2] = mn;
        float sj[4];
#pragma unroll
        for (int j = 0; j < 4; ++j) sj[j] = __shfl(scl, lg * 4 + j);
#pragma unroll
        for (int j = 0; j < 4; ++j) osum[t2][j] *= sj[j];
#pragma unroll
        for (int nb = 0; nb < 8; ++nb)
#pragma unroll
          for (int j = 0; j < 4; ++j) oacc[t2][nb][j] *= sj[j];
      }
    }

    // P = exp2(S2 - m2)
#pragma unroll
    for (int t2 = 0; t2 < 2; ++t2)
#pragma unroll
      for (int nf = 0; nf < 4; ++nf)
#pragma unroll
        for (int j = 0; j < 4; ++j)
          st[t2][nf][j] = exp2f(st[t2][nf][j] - mrun[t2]);

    // pack PV A-frags
    bf16x8 pa[2][2];
#pragma unroll
    for (int t2 = 0; t2 < 2; ++t2)
#pragma unroll
      for (int kk = 0; kk < 2; ++kk) {
        union { unsigned int u[4]; bf16x8 v; } w_;
        w_.u[0] = cvtpk(st[t2][kk][0], st[t2][kk][1]);
        w_.u[1] = cvtpk(st[t2][kk][2], st[t2][kk][3]);
        w_.u[2] = cvtpk(st[t2][2 + kk][0], st[t2][2 + kk][1]);
        w_.u[3] = cvtpk(st[t2][2 + kk][2], st[t2][2 + kk][3]);
        pa[t2][kk] = w_.v;
      }

    // PV + row-sum via ones-MFMA
    __builtin_amdgcn_s_setprio(1);
#pragma unroll
    for (int t2 = 0; t2 < 2; ++t2) {
      osum[t2] = __builtin_amdgcn_mfma_f32_16x16x32_bf16(pa[t2][0], ones, osum[t2], 0, 0, 0);
      osum[t2] = __builtin_amdgcn_mfma_f32_16x16x32_bf16(pa[t2][1], ones, osum[t2], 0, 0, 0);
    }
#pragma unroll
    for (int nb = 0; nb < 8; ++nb)
#pragma unroll
      for (int kk = 0; kk < 2; ++kk) {
        int pc = (kk * 4 + lg) ^ (lm & 7);
        bf16x8 vfrag = *reinterpret_cast<const bf16x8*>(&Vc[(nb * 16 + lm) * 64 + pc * 8]);
        oacc[0][nb] = __builtin_amdgcn_mfma_f32_16x16x32_bf16(pa[0][kk], vfrag, oacc[0][nb], 0, 0, 0);
        oacc[1][nb] = __builtin_amdgcn_mfma_f32_16x16x32_bf16(pa[1][kk], vfrag, oacc[1][nb], 0, 0, 0);
      }
    __builtin_amdgcn_s_setprio(0);

    __syncthreads();
  }

  // epilogue
#pragma unroll
  for (int t2 = 0; t2 < 2; ++t2) {
    float linv[4];
#pragma unroll
    for (int j = 0; j < 4; ++j) linv[j] = 1.0f / osum[t2][j];
#pragma unroll
    for (int nb = 0; nb < 8; ++nb)
#pragma unroll
      for (int j = 0; j < 4; ++j) {
        int row = q0 + wave * 32 + t2 * 16 + lg * 4 + j;
        int col = h * HEADDIM + nb * 16 + lm;
        float ov = oacc[t2][nb][j] * linv[j];
        ushort hi, lo;
        splitf(ov, hi, lo);
        Oh[(size_t)row * DMODEL + col] = hi;
        Ol[(size_t)row * DMODEL + col] = lo;
      }
  }
}

extern "C" void kernel_launch(void* const* d_in, const int* in_sizes, int n_in,
                              void* d_out, int out_size, void* d_ws, size_t ws_size,
                              hipStream_t stream) {
  (void)in_sizes; (void)n_in; (void)out_size; (void)ws_size;
  const float* X  = (const float*)d_in[0];
  const float* Wq = (const float*)d_in[1];
  const float* Wk = (const float*)d_in[2];
  const float* Wv = (const float*)d_in[3];
  const float* Wo = (const float*)d_in[4];
  const int* pos  = (const int*)d_in[5];
  float* out = (float*)d_out;

  ushort* wb = (ushort*)d_ws;
  const size_t SD = (size_t)S_LEN * DMODEL;       // 8388608 elements
  const size_t DD = (size_t)DMODEL * DMODEL;      // 4194304 elements

  ushort* Xh   = wb;                 // slot0
  ushort* OlB  = wb + SD;            // slot1
  ushort* QKV  = wb + 2 * SD;        // slots 2-4: [4096][6144]
  ushort* Vt   = wb + 5 * SD;        // slot5: [2048][4096]
  ushort* W0h  = wb + 6 * SD;        // Wo hi
  ushort* W0l  = wb + 6 * SD + DD;   // Wo lo
  ushort* Wqkv = wb + 7 * SD;        // [6144][2048] (3 DD, fits in slots 7-8)
  float* cosT  = (float*)(wb + 9 * SD);
  float* sinT  = cosT + (size_t)S_LEN * 64;
  ushort* OhB  = Wqkv;               // reuse after QKV GEMM done

  rope_table_kernel<<<S_LEN * 64 / 256, 256, 0, stream>>>(cosT, sinT);
  convert_kernel<<<SD / 1024, 256, 0, stream>>>(X, Xh);
  prep_weights<<<dim3(DD / 1024, 4), 256, 0, stream>>>(Wq, Wk, Wv, Wo, Wqkv, W0h, W0l);

  gemm_qkv<<<dim3(LDQ / 128, S_LEN / 128), 256, 0, stream>>>(Xh, Wqkv, QKV, S_LEN, LDQ, DMODEL);

  rope2_kernel<<<(S_LEN * 1024) / 256, 256, 0, stream>>>(QKV, pos, cosT, sinT);
  transpose_kernel<<<dim3(S_LEN / 64, DMODEL / 64), 256, 0, stream>>>(QKV + 2 * DMODEL, Vt);

  flash10_kernel<<<dim3(32, 16), 256, 0, stream>>>(QKV, Vt, OhB, OlB);

  dim3 gemmGrid(DMODEL / 128, S_LEN / 128);
  gemm3<<<gemmGrid, 256, 0, stream>>>(OhB, OlB, W0h, W0l, out, S_LEN, DMODEL, DMODEL);
}

// Round 10
// 380.200 us; speedup vs baseline: 1.6932x; 1.1295x over previous
//
#include <hip/hip_runtime.h>
#include <hip/hip_bf16.h>

#define S_LEN 4096
#define DMODEL 2048
#define NHEADS 16
#define HEADDIM 128
#define LDQ 6144  // stride of fused QKV buffer

typedef __attribute__((ext_vector_type(8))) short bf16x8;
typedef __attribute__((ext_vector_type(4))) float f32x4;

__device__ __forceinline__ float bf2f(ushort u) {
  union { unsigned int i; float f; } x; x.i = ((unsigned int)u) << 16; return x.f;
}
__device__ __forceinline__ ushort f2bf(float f) {
  union { float f; unsigned int i; } x; x.f = f;
  unsigned int u = x.i;
  unsigned int r = u + 0x7fffu + ((u >> 16) & 1u);
  return (ushort)(r >> 16);
}
__device__ __forceinline__ void splitf(float f, ushort& h, ushort& l) {
  unsigned int u = __float_as_uint(f);
  h = (ushort)(u >> 16);
  l = f2bf(f - __uint_as_float(u & 0xffff0000u));
}
__device__ __forceinline__ unsigned int cvtpk(float a, float b) {
  unsigned int r;
  asm("v_cvt_pk_bf16_f32 %0, %1, %2" : "=v"(r) : "v"(a), "v"(b));
  return r;
}
// fast hardware exp2 (v_exp_f32 IS 2^x); bypasses ocml's precise/denormal path
__device__ __forceinline__ float fexp2(float x) {
  float r;
  asm("v_exp_f32 %0, %1" : "=v"(r) : "v"(x));
  return r;
}

__device__ __forceinline__ void gload16(const ushort* g, ushort* l) {
  __builtin_amdgcn_global_load_lds(
      (const __attribute__((address_space(1))) unsigned int*)g,
      (__attribute__((address_space(3))) unsigned int*)l, 16, 0, 0);
}

// ---------------- RoPE cos/sin table ----------------
__global__ __launch_bounds__(256) void rope_table_kernel(float* __restrict__ cosT,
                                                         float* __restrict__ sinT) {
  int idx = blockIdx.x * 256 + threadIdx.x;
  int t = idx >> 6, j = idx & 63;
  float expo = (float)(2 * j) / 128.0f;
  float inv = 1.0f / powf(10000.0f, expo);
  float f = (float)t * inv;
  cosT[idx] = cosf(f);
  sinT[idx] = sinf(f);
}

// ---------------- fp32 -> bf16 (RNE) convert ----------------
__global__ __launch_bounds__(256) void convert_kernel(const float* __restrict__ in,
                                                      ushort* __restrict__ hi) {
  int i = (blockIdx.x * 256 + threadIdx.x) * 4;
  float4 v = *reinterpret_cast<const float4*>(&in[i]);
  ushort4 h;
  h.x = f2bf(v.x); h.y = f2bf(v.y); h.z = f2bf(v.z); h.w = f2bf(v.w);
  *reinterpret_cast<ushort4*>(&hi[i]) = h;
}

// ---------------- weight prep: Wq/Wk/Wv -> packed bf16 [6144][2048]; Wo -> bf16 ----------------
__global__ __launch_bounds__(256) void prep_weights(const float* __restrict__ Wq,
                                                    const float* __restrict__ Wk,
                                                    const float* __restrict__ Wv,
                                                    const float* __restrict__ Wo,
                                                    ushort* __restrict__ Wqkv,
                                                    ushort* __restrict__ Woh) {
  int i = (blockIdx.x * 256 + threadIdx.x) * 4;
  int which = blockIdx.y;
  const float* src = (which == 0) ? Wq : (which == 1) ? Wk : (which == 2) ? Wv : Wo;
  ushort* dst = (which == 3) ? Woh : (Wqkv + (size_t)which * DMODEL * DMODEL);
  float4 v = *reinterpret_cast<const float4*>(&src[i]);
  ushort4 h;
  h.x = f2bf(v.x); h.y = f2bf(v.y); h.z = f2bf(v.z); h.w = f2bf(v.w);
  *reinterpret_cast<ushort4*>(&dst[i]) = h;
}

// ---------------- fused QKV GEMM: QKV = Xh * Wqkv^T, BK=64, 128x128 tile ----------------
__global__ __launch_bounds__(256) void gemm_qkv(const ushort* __restrict__ Ah_,
                                                const ushort* __restrict__ Bh_,
                                                ushort* __restrict__ Cout,
                                                int M, int N, int K) {
  __shared__ __align__(16) ushort sAh[128 * 64], sBh[128 * 64];
  const int tid = threadIdx.x;
  const int wave = tid >> 6, lane = tid & 63;
  const int lg = lane >> 4, lm = lane & 15;
  const int nwg = gridDim.x * gridDim.y;
  const int id = blockIdx.y * gridDim.x + blockIdx.x;
  const int cpx = nwg >> 3;
  const int swz = (id & 7) * cpx + (id >> 3);
  const int nbx = N >> 7;
  const int m0 = (swz / nbx) * 128, n0 = (swz % nbx) * 128;
  const int wm = (wave >> 1) * 64, wn = (wave & 1) * 64;
  f32x4 acc[4][4] = {};

  int srow[4], scc[4], lbs[4];
#pragma unroll
  for (int it = 0; it < 4; ++it) {
    int ci = it * 256 + wave * 64 + lane;
    srow[it] = ci >> 3;
    scc[it] = (ci & 7) ^ (srow[it] & 7);
    lbs[it] = (it * 256 + wave * 64) * 8;
  }

  for (int k0 = 0; k0 < K; k0 += 64) {
    __syncthreads();
#pragma unroll
    for (int it = 0; it < 4; ++it) {
      size_t ga = (size_t)(m0 + srow[it]) * K + k0 + scc[it] * 8;
      size_t gb = (size_t)(n0 + srow[it]) * K + k0 + scc[it] * 8;
      gload16(&Ah_[ga], &sAh[lbs[it]]);
      gload16(&Bh_[gb], &sBh[lbs[it]]);
    }
    __syncthreads();
    bf16x8 ah[4][2], bh[4][2];
#pragma unroll
    for (int t = 0; t < 4; ++t)
#pragma unroll
      for (int kc = 0; kc < 2; ++kc) {
        int Ra = wm + t * 16 + lm;
        int Rb = wn + t * 16 + lm;
        int pa_ = ((kc * 4 + lg) ^ (Ra & 7)) * 8;
        int pb_ = ((kc * 4 + lg) ^ (Rb & 7)) * 8;
        ah[t][kc] = *reinterpret_cast<const bf16x8*>(&sAh[Ra * 64 + pa_]);
        bh[t][kc] = *reinterpret_cast<const bf16x8*>(&sBh[Rb * 64 + pb_]);
      }
#pragma unroll
    for (int kc = 0; kc < 2; ++kc)
#pragma unroll
      for (int mi = 0; mi < 4; ++mi)
#pragma unroll
        for (int ni = 0; ni < 4; ++ni)
          acc[mi][ni] = __builtin_amdgcn_mfma_f32_16x16x32_bf16(ah[mi][kc], bh[ni][kc], acc[mi][ni], 0, 0, 0);
  }
#pragma unroll
  for (int mi = 0; mi < 4; ++mi)
#pragma unroll
    for (int ni = 0; ni < 4; ++ni)
#pragma unroll
      for (int j = 0; j < 4; ++j) {
        int row = m0 + wm + mi * 16 + lg * 4 + j;
        int col = n0 + wn + ni * 16 + lm;
        Cout[(size_t)row * N + col] = f2bf(acc[mi][ni][j]);
      }
}

// ---------------- 2-term final GEMM: out = (Oh+Ol) * Woh^T (f32 out) ----------------
__global__ __launch_bounds__(256) void gemm2o(const ushort* __restrict__ Ah_,
                                              const ushort* __restrict__ Al_,
                                              const ushort* __restrict__ Bh_,
                                              float* __restrict__ Cout,
                                              int M, int N, int K) {
  __shared__ __align__(16) ushort sAh[128 * 32], sAl[128 * 32], sBh[128 * 32];
  const int tid = threadIdx.x;
  const int wave = tid >> 6, lane = tid & 63;
  const int lg = lane >> 4, lm = lane & 15;
  const int nwg = gridDim.x * gridDim.y;
  const int id = blockIdx.y * gridDim.x + blockIdx.x;
  const int cpx = nwg >> 3;
  const int swz = (id & 7) * cpx + (id >> 3);
  const int nbx = N >> 7;
  const int m0 = (swz / nbx) * 128, n0 = (swz % nbx) * 128;
  const int wm = (wave >> 1) * 64, wn = (wave & 1) * 64;
  f32x4 acc[4][4] = {};

  for (int k0 = 0; k0 < K; k0 += 32) {
    __syncthreads();
#pragma unroll
    for (int t = 0; t < 2; ++t) {
      int r = wave * 32 + t * 16 + (lane >> 2);
      int ca = (lane & 3) ^ ((r >> 1) & 3);
      size_t ga = (size_t)(m0 + r) * K + k0 + ca * 8;
      size_t gb = (size_t)(n0 + r) * K + k0 + ca * 8;
      int lb = (wave * 32 + t * 16) * 32;
      gload16(&Ah_[ga], &sAh[lb]);
      gload16(&Al_[ga], &sAl[lb]);
      gload16(&Bh_[gb], &sBh[lb]);
    }
    __syncthreads();
    bf16x8 ah[4], al[4], bh[4];
#pragma unroll
    for (int t = 0; t < 4; ++t) {
      int Ra = wm + t * 16 + lm;
      int Rb = wn + t * 16 + lm;
      int ca = (lg ^ ((Ra >> 1) & 3)) * 8;
      int cb = (lg ^ ((Rb >> 1) & 3)) * 8;
      ah[t] = *reinterpret_cast<const bf16x8*>(&sAh[Ra * 32 + ca]);
      al[t] = *reinterpret_cast<const bf16x8*>(&sAl[Ra * 32 + ca]);
      bh[t] = *reinterpret_cast<const bf16x8*>(&sBh[Rb * 32 + cb]);
    }
#pragma unroll
    for (int mi = 0; mi < 4; ++mi)
#pragma unroll
      for (int ni = 0; ni < 4; ++ni) {
        acc[mi][ni] = __builtin_amdgcn_mfma_f32_16x16x32_bf16(ah[mi], bh[ni], acc[mi][ni], 0, 0, 0);
        acc[mi][ni] = __builtin_amdgcn_mfma_f32_16x16x32_bf16(al[mi], bh[ni], acc[mi][ni], 0, 0, 0);
      }
  }
#pragma unroll
  for (int mi = 0; mi < 4; ++mi)
#pragma unroll
    for (int ni = 0; ni < 4; ++ni)
#pragma unroll
      for (int j = 0; j < 4; ++j) {
        int row = m0 + wm + mi * 16 + lg * 4 + j;
        int col = n0 + wn + ni * 16 + lm;
        Cout[(size_t)row * N + col] = acc[mi][ni][j];
      }
}

// ---------------- RoPE in-place on QKV buffer: Q scaled by log2e/sqrt(HD) ----------------
__global__ __launch_bounds__(256) void rope2_kernel(ushort* __restrict__ QKV,
                                                    const int* __restrict__ pos,
                                                    const float* __restrict__ cosT,
                                                    const float* __restrict__ sinT) {
  int idx = blockIdx.x * 256 + threadIdx.x;
  int s = idx >> 10, dh = idx & 1023;
  int hh = dh >> 6, j = dh & 63;
  int p = pos[s];
  float cs = cosT[p * 64 + j], sn = sinT[p * 64 + j];
  size_t i1 = (size_t)s * LDQ + hh * HEADDIM + j, i2 = i1 + 64;
  size_t k1i = i1 + DMODEL, k2i = i2 + DMODEL;
  float q1 = bf2f(QKV[i1]), q2 = bf2f(QKV[i2]);
  float k1 = bf2f(QKV[k1i]), k2 = bf2f(QKV[k2i]);
  const float scl = 0.12751742f;  // log2(e)/sqrt(128)
  QKV[i1] = f2bf((q1 * cs - q2 * sn) * scl);
  QKV[i2] = f2bf((q2 * cs + q1 * sn) * scl);
  QKV[k1i] = f2bf(k1 * cs - k2 * sn);
  QKV[k2i] = f2bf(k2 * cs + k1 * sn);
}

// ---------------- V transpose: QKV V-columns -> Vt [2048][S] ----------------
__global__ __launch_bounds__(256) void transpose_kernel(const ushort* __restrict__ Vr,
                                                        ushort* __restrict__ Vt) {
  __shared__ __align__(16) ushort tile[64 * 72];
  int tid = threadIdx.x;
  int s0 = blockIdx.x * 64, c0 = blockIdx.y * 64;
#pragma unroll
  for (int it = 0; it < 2; ++it) {
    int i = tid + it * 256;
    int r = i >> 3, c = i & 7;
    *reinterpret_cast<uint4*>(&tile[r * 72 + c * 8]) =
        *reinterpret_cast<const uint4*>(&Vr[(size_t)(s0 + r) * LDQ + c0 + c * 8]);
  }
  __syncthreads();
#pragma unroll
  for (int it = 0; it < 2; ++it) {
    int i = tid + it * 256;
    int cr = i >> 3, sc = i & 7;
    ushort tmp[8];
#pragma unroll
    for (int j = 0; j < 8; ++j) tmp[j] = tile[(sc * 8 + j) * 72 + cr];
    *reinterpret_cast<uint4*>(&Vt[(size_t)(c0 + cr) * S_LEN + s0 + sc * 8]) =
        *reinterpret_cast<uint4*>(tmp);
  }
}

// ---------------- Flash attention v11 = flash10 + fast v_exp_f32 ----------------
__global__ __launch_bounds__(256, 2) void flash11_kernel(const ushort* __restrict__ QKV,
                                                         const ushort* __restrict__ Vt,
                                                         ushort* __restrict__ Oh,
                                                         ushort* __restrict__ Ol) {
  __shared__ __align__(16) ushort Kt[2][64 * 128];
  __shared__ __align__(16) ushort Vs[2][128 * 64];
  const int tid = threadIdx.x;             // 0..255
  const int wave = tid >> 6, lane = tid & 63;
  const int lg = lane >> 4, lm = lane & 15;
  const int id = blockIdx.y * gridDim.x + blockIdx.x;  // 0..511
  const int o = (id & 7) * 64 + (id >> 3);             // XCD swizzle (512 = 8*64)
  const int h = o >> 5;
  const int q0 = (o & 31) * 128;

  bf16x8 qh[2][4];
#pragma unroll
  for (int t2 = 0; t2 < 2; ++t2) {
    int qrow = q0 + wave * 32 + t2 * 16 + lm;
#pragma unroll
    for (int kc = 0; kc < 4; ++kc)
      qh[t2][kc] = *reinterpret_cast<const bf16x8*>(
          &QKV[(size_t)qrow * LDQ + h * HEADDIM + kc * 32 + lg * 8]);
  }

  bf16x8 ones;
#pragma unroll
  for (int i = 0; i < 8; ++i) ones[i] = (short)0x3f80;  // bf16 1.0

  auto rho = [](int s) {
    return 32 * ((s >> 4) & 1) + 8 * ((s >> 2) & 3) + 4 * (s >> 5) + (s & 3);
  };
  const ushort* Kb = QKV + DMODEL;  // K columns
  const ushort* pK[4];
  const ushort* pV[4];
  int lbs[4];
#pragma unroll
  for (int k = 0; k < 4; ++k) {
    int ci = k * 256 + wave * 64 + lane;
    int ks = ci >> 4;
    int kcc = (ci & 15) ^ (ks & 7);
    pK[k] = Kb + (size_t)rho(ks) * LDQ + h * HEADDIM + kcc * 8;
    int vd = ci >> 3;
    int vcc = (ci & 7) ^ (vd & 7);
    pV[k] = Vt + (size_t)(h * HEADDIM + vd) * S_LEN + vcc * 8;
    lbs[k] = (k * 256 + wave * 64) * 8;
  }

  f32x4 oacc[2][8] = {};
  f32x4 osum[2] = {};
  float mrun[2];
#pragma unroll
  for (int t2 = 0; t2 < 2; ++t2) mrun[t2] = -3.0e38f;

#pragma unroll
  for (int k = 0; k < 4; ++k) {
    gload16(pK[k], &Kt[0][lbs[k]]);
    gload16(pV[k], &Vs[0][lbs[k]]);
  }
  __syncthreads();

  for (int t = 0; t < S_LEN / 64; ++t) {
    const int cur = t & 1;
    if (t < S_LEN / 64 - 1) {
      const size_t koff = (size_t)(t + 1) * 64;
#pragma unroll
      for (int k = 0; k < 4; ++k) {
        gload16(pK[k] + koff * LDQ, &Kt[cur ^ 1][lbs[k]]);
        gload16(pV[k] + koff, &Vs[cur ^ 1][lbs[k]]);
      }
    }
    const ushort* Kc = &Kt[cur][0];
    const ushort* Vc = &Vs[cur][0];

    // QK^T swapped
    f32x4 st[2][4] = {};
    __builtin_amdgcn_s_setprio(1);
#pragma unroll
    for (int nf = 0; nf < 4; ++nf)
#pragma unroll
      for (int kc = 0; kc < 4; ++kc) {
        int pc = (kc * 4 + lg) ^ (lm & 7);
        bf16x8 kfrag = *reinterpret_cast<const bf16x8*>(&Kc[(nf * 16 + lm) * 128 + pc * 8]);
        st[0][nf] = __builtin_amdgcn_mfma_f32_16x16x32_bf16(kfrag, qh[0][kc], st[0][nf], 0, 0, 0);
        st[1][nf] = __builtin_amdgcn_mfma_f32_16x16x32_bf16(kfrag, qh[1][kc], st[1][nf], 0, 0, 0);
      }
    __builtin_amdgcn_s_setprio(0);

    // row max
    float m16[2];
#pragma unroll
    for (int t2 = 0; t2 < 2; ++t2) {
      float m = fmaxf(st[t2][0][0], st[t2][0][1]);
      m = fmaxf(fmaxf(m, st[t2][0][2]), st[t2][0][3]);
      m = fmaxf(fmaxf(m, st[t2][1][0]), st[t2][1][1]);
      m = fmaxf(fmaxf(m, st[t2][1][2]), st[t2][1][3]);
      m = fmaxf(fmaxf(m, st[t2][2][0]), st[t2][2][1]);
      m = fmaxf(fmaxf(m, st[t2][2][2]), st[t2][2][3]);
      m = fmaxf(fmaxf(m, st[t2][3][0]), st[t2][3][1]);
      m = fmaxf(fmaxf(m, st[t2][3][2]), st[t2][3][3]);
      m = fmaxf(m, __shfl_xor(m, 16));
      m = fmaxf(m, __shfl_xor(m, 32));
      m16[t2] = m;
    }

    // defer-max rescale (exp2 domain, thr 11.5 ~= 8*log2e)
    bool grow = (m16[0] > mrun[0] + 11.5f) || (m16[1] > mrun[1] + 11.5f);
    if (__any(grow)) {
#pragma unroll
      for (int t2 = 0; t2 < 2; ++t2) {
        float mn = fmaxf(mrun[t2], m16[t2]);
        float scl = fexp2(mrun[t2] - mn);
        mrun[t2] = mn;
        float sj[4];
#pragma unroll
        for (int j = 0; j < 4; ++j) sj[j] = __shfl(scl, lg * 4 + j);
#pragma unroll
        for (int j = 0; j < 4; ++j) osum[t2][j] *= sj[j];
#pragma unroll
        for (int nb = 0; nb < 8; ++nb)
#pragma unroll
          for (int j = 0; j < 4; ++j) oacc[t2][nb][j] *= sj[j];
      }
    }

    // P = exp2(S2 - m2) via raw v_exp_f32
#pragma unroll
    for (int t2 = 0; t2 < 2; ++t2)
#pragma unroll
      for (int nf = 0; nf < 4; ++nf)
#pragma unroll
        for (int j = 0; j < 4; ++j)
          st[t2][nf][j] = fexp2(st[t2][nf][j] - mrun[t2]);

    // pack PV A-frags
    bf16x8 pa[2][2];
#pragma unroll
    for (int t2 = 0; t2 < 2; ++t2)
#pragma unroll
      for (int kk = 0; kk < 2; ++kk) {
        union { unsigned int u[4]; bf16x8 v; } w_;
        w_.u[0] = cvtpk(st[t2][kk][0], st[t2][kk][1]);
        w_.u[1] = cvtpk(st[t2][kk][2], st[t2][kk][3]);
        w_.u[2] = cvtpk(st[t2][2 + kk][0], st[t2][2 + kk][1]);
        w_.u[3] = cvtpk(st[t2][2 + kk][2], st[t2][2 + kk][3]);
        pa[t2][kk] = w_.v;
      }

    // PV + row-sum via ones-MFMA
    __builtin_amdgcn_s_setprio(1);
#pragma unroll
    for (int t2 = 0; t2 < 2; ++t2) {
      osum[t2] = __builtin_amdgcn_mfma_f32_16x16x32_bf16(pa[t2][0], ones, osum[t2], 0, 0, 0);
      osum[t2] = __builtin_amdgcn_mfma_f32_16x16x32_bf16(pa[t2][1], ones, osum[t2], 0, 0, 0);
    }
#pragma unroll
    for (int nb = 0; nb < 8; ++nb)
#pragma unroll
      for (int kk = 0; kk < 2; ++kk) {
        int pc = (kk * 4 + lg) ^ (lm & 7);
        bf16x8 vfrag = *reinterpret_cast<const bf16x8*>(&Vc[(nb * 16 + lm) * 64 + pc * 8]);
        oacc[0][nb] = __builtin_amdgcn_mfma_f32_16x16x32_bf16(pa[0][kk], vfrag, oacc[0][nb], 0, 0, 0);
        oacc[1][nb] = __builtin_amdgcn_mfma_f32_16x16x32_bf16(pa[1][kk], vfrag, oacc[1][nb], 0, 0, 0);
      }
    __builtin_amdgcn_s_setprio(0);

    __syncthreads();
  }

  // epilogue
#pragma unroll
  for (int t2 = 0; t2 < 2; ++t2) {
    float linv[4];
#pragma unroll
    for (int j = 0; j < 4; ++j) linv[j] = 1.0f / osum[t2][j];
#pragma unroll
    for (int nb = 0; nb < 8; ++nb)
#pragma unroll
      for (int j = 0; j < 4; ++j) {
        int row = q0 + wave * 32 + t2 * 16 + lg * 4 + j;
        int col = h * HEADDIM + nb * 16 + lm;
        float ov = oacc[t2][nb][j] * linv[j];
        ushort hi, lo;
        splitf(ov, hi, lo);
        Oh[(size_t)row * DMODEL + col] = hi;
        Ol[(size_t)row * DMODEL + col] = lo;
      }
  }
}

extern "C" void kernel_launch(void* const* d_in, const int* in_sizes, int n_in,
                              void* d_out, int out_size, void* d_ws, size_t ws_size,
                              hipStream_t stream) {
  (void)in_sizes; (void)n_in; (void)out_size; (void)ws_size;
  const float* X  = (const float*)d_in[0];
  const float* Wq = (const float*)d_in[1];
  const float* Wk = (const float*)d_in[2];
  const float* Wv = (const float*)d_in[3];
  const float* Wo = (const float*)d_in[4];
  const int* pos  = (const int*)d_in[5];
  float* out = (float*)d_out;

  ushort* wb = (ushort*)d_ws;
  const size_t SD = (size_t)S_LEN * DMODEL;       // 8388608 elements
  const size_t DD = (size_t)DMODEL * DMODEL;      // 4194304 elements

  ushort* Xh   = wb;                 // slot0
  ushort* OlB  = wb + SD;            // slot1
  ushort* QKV  = wb + 2 * SD;        // slots 2-4: [4096][6144]
  ushort* Vt   = wb + 5 * SD;        // slot5: [2048][4096]
  ushort* W0h  = wb + 6 * SD;        // Wo bf16
  ushort* Wqkv = wb + 7 * SD;        // [6144][2048]
  float* cosT  = (float*)(wb + 9 * SD);
  float* sinT  = cosT + (size_t)S_LEN * 64;
  ushort* OhB  = Wqkv;               // reuse after QKV GEMM done

  rope_table_kernel<<<S_LEN * 64 / 256, 256, 0, stream>>>(cosT, sinT);
  convert_kernel<<<SD / 1024, 256, 0, stream>>>(X, Xh);
  prep_weights<<<dim3(DD / 1024, 4), 256, 0, stream>>>(Wq, Wk, Wv, Wo, Wqkv, W0h);

  gemm_qkv<<<dim3(LDQ / 128, S_LEN / 128), 256, 0, stream>>>(Xh, Wqkv, QKV, S_LEN, LDQ, DMODEL);

  rope2_kernel<<<(S_LEN * 1024) / 256, 256, 0, stream>>>(QKV, pos, cosT, sinT);
  transpose_kernel<<<dim3(S_LEN / 64, DMODEL / 64), 256, 0, stream>>>(QKV + 2 * DMODEL, Vt);

  flash11_kernel<<<dim3(32, 16), 256, 0, stream>>>(QKV, Vt, OhB, OlB);

  dim3 gemmGrid(DMODEL / 128, S_LEN / 128);
  gemm2o<<<gemmGrid, 256, 0, stream>>>(OhB, OlB, W0h, out, S_LEN, DMODEL, DMODEL);
}

// Round 11
// 349.880 us; speedup vs baseline: 1.8399x; 1.0867x over previous
//
#include <hip/hip_runtime.h>
#include <hip/hip_bf16.h>

#define S_LEN 4096
#define DMODEL 2048
#define NHEADS 16
#define HEADDIM 128
#define LDQ 6144  // stride of fused QKV buffer

typedef __attribute__((ext_vector_type(8))) short bf16x8;
typedef __attribute__((ext_vector_type(4))) float f32x4;

__device__ __forceinline__ float bf2f(ushort u) {
  union { unsigned int i; float f; } x; x.i = ((unsigned int)u) << 16; return x.f;
}
__device__ __forceinline__ ushort f2bf(float f) {
  union { float f; unsigned int i; } x; x.f = f;
  unsigned int u = x.i;
  unsigned int r = u + 0x7fffu + ((u >> 16) & 1u);
  return (ushort)(r >> 16);
}
__device__ __forceinline__ unsigned int cvtpk(float a, float b) {
  unsigned int r;
  asm("v_cvt_pk_bf16_f32 %0, %1, %2" : "=v"(r) : "v"(a), "v"(b));
  return r;
}
// fast hardware exp2 (v_exp_f32 IS 2^x); bypasses ocml's precise path
__device__ __forceinline__ float fexp2(float x) {
  float r;
  asm("v_exp_f32 %0, %1" : "=v"(r) : "v"(x));
  return r;
}

__device__ __forceinline__ void gload16(const ushort* g, ushort* l) {
  __builtin_amdgcn_global_load_lds(
      (const __attribute__((address_space(1))) unsigned int*)g,
      (__attribute__((address_space(3))) unsigned int*)l, 16, 0, 0);
}

// ---------------- RoPE cos/sin table ----------------
__global__ __launch_bounds__(256) void rope_table_kernel(float* __restrict__ cosT,
                                                         float* __restrict__ sinT) {
  int idx = blockIdx.x * 256 + threadIdx.x;
  int t = idx >> 6, j = idx & 63;
  float expo = (float)(2 * j) / 128.0f;
  float inv = 1.0f / powf(10000.0f, expo);
  float f = (float)t * inv;
  cosT[idx] = cosf(f);
  sinT[idx] = sinf(f);
}

// ---------------- fp32 -> bf16 (RNE) convert ----------------
__global__ __launch_bounds__(256) void convert_kernel(const float* __restrict__ in,
                                                      ushort* __restrict__ hi) {
  int i = (blockIdx.x * 256 + threadIdx.x) * 4;
  float4 v = *reinterpret_cast<const float4*>(&in[i]);
  ushort4 h;
  h.x = f2bf(v.x); h.y = f2bf(v.y); h.z = f2bf(v.z); h.w = f2bf(v.w);
  *reinterpret_cast<ushort4*>(&hi[i]) = h;
}

// ---------------- weight prep: Wq/Wk/Wv -> packed bf16 [6144][2048]; Wo -> bf16 ----------------
__global__ __launch_bounds__(256) void prep_weights(const float* __restrict__ Wq,
                                                    const float* __restrict__ Wk,
                                                    const float* __restrict__ Wv,
                                                    const float* __restrict__ Wo,
                                                    ushort* __restrict__ Wqkv,
                                                    ushort* __restrict__ Woh) {
  int i = (blockIdx.x * 256 + threadIdx.x) * 4;
  int which = blockIdx.y;
  const float* src = (which == 0) ? Wq : (which == 1) ? Wk : (which == 2) ? Wv : Wo;
  ushort* dst = (which == 3) ? Woh : (Wqkv + (size_t)which * DMODEL * DMODEL);
  float4 v = *reinterpret_cast<const float4*>(&src[i]);
  ushort4 h;
  h.x = f2bf(v.x); h.y = f2bf(v.y); h.z = f2bf(v.z); h.w = f2bf(v.w);
  *reinterpret_cast<ushort4*>(&dst[i]) = h;
}

// ---------------- fused QKV GEMM: QKV = Xh * Wqkv^T, BK=64, 128x128 tile ----------------
__global__ __launch_bounds__(256) void gemm_qkv(const ushort* __restrict__ Ah_,
                                                const ushort* __restrict__ Bh_,
                                                ushort* __restrict__ Cout,
                                                int M, int N, int K) {
  __shared__ __align__(16) ushort sAh[128 * 64], sBh[128 * 64];
  const int tid = threadIdx.x;
  const int wave = tid >> 6, lane = tid & 63;
  const int lg = lane >> 4, lm = lane & 15;
  const int nwg = gridDim.x * gridDim.y;
  const int id = blockIdx.y * gridDim.x + blockIdx.x;
  const int cpx = nwg >> 3;
  const int swz = (id & 7) * cpx + (id >> 3);
  const int nbx = N >> 7;
  const int m0 = (swz / nbx) * 128, n0 = (swz % nbx) * 128;
  const int wm = (wave >> 1) * 64, wn = (wave & 1) * 64;
  f32x4 acc[4][4] = {};

  int srow[4], scc[4], lbs[4];
#pragma unroll
  for (int it = 0; it < 4; ++it) {
    int ci = it * 256 + wave * 64 + lane;
    srow[it] = ci >> 3;
    scc[it] = (ci & 7) ^ (srow[it] & 7);
    lbs[it] = (it * 256 + wave * 64) * 8;
  }

  for (int k0 = 0; k0 < K; k0 += 64) {
    __syncthreads();
#pragma unroll
    for (int it = 0; it < 4; ++it) {
      size_t ga = (size_t)(m0 + srow[it]) * K + k0 + scc[it] * 8;
      size_t gb = (size_t)(n0 + srow[it]) * K + k0 + scc[it] * 8;
      gload16(&Ah_[ga], &sAh[lbs[it]]);
      gload16(&Bh_[gb], &sBh[lbs[it]]);
    }
    __syncthreads();
    bf16x8 ah[4][2], bh[4][2];
#pragma unroll
    for (int t = 0; t < 4; ++t)
#pragma unroll
      for (int kc = 0; kc < 2; ++kc) {
        int Ra = wm + t * 16 + lm;
        int Rb = wn + t * 16 + lm;
        int pa_ = ((kc * 4 + lg) ^ (Ra & 7)) * 8;
        int pb_ = ((kc * 4 + lg) ^ (Rb & 7)) * 8;
        ah[t][kc] = *reinterpret_cast<const bf16x8*>(&sAh[Ra * 64 + pa_]);
        bh[t][kc] = *reinterpret_cast<const bf16x8*>(&sBh[Rb * 64 + pb_]);
      }
#pragma unroll
    for (int kc = 0; kc < 2; ++kc)
#pragma unroll
      for (int mi = 0; mi < 4; ++mi)
#pragma unroll
        for (int ni = 0; ni < 4; ++ni)
          acc[mi][ni] = __builtin_amdgcn_mfma_f32_16x16x32_bf16(ah[mi][kc], bh[ni][kc], acc[mi][ni], 0, 0, 0);
  }
#pragma unroll
  for (int mi = 0; mi < 4; ++mi)
#pragma unroll
    for (int ni = 0; ni < 4; ++ni)
#pragma unroll
      for (int j = 0; j < 4; ++j) {
        int row = m0 + wm + mi * 16 + lg * 4 + j;
        int col = n0 + wn + ni * 16 + lm;
        Cout[(size_t)row * N + col] = f2bf(acc[mi][ni][j]);
      }
}

// ---------------- 1-term final GEMM: out = Oh * Woh^T (f32 out) ----------------
__global__ __launch_bounds__(256) void gemm1o(const ushort* __restrict__ Ah_,
                                              const ushort* __restrict__ Bh_,
                                              float* __restrict__ Cout,
                                              int M, int N, int K) {
  __shared__ __align__(16) ushort sAh[128 * 32], sBh[128 * 32];
  const int tid = threadIdx.x;
  const int wave = tid >> 6, lane = tid & 63;
  const int lg = lane >> 4, lm = lane & 15;
  const int nwg = gridDim.x * gridDim.y;
  const int id = blockIdx.y * gridDim.x + blockIdx.x;
  const int cpx = nwg >> 3;
  const int swz = (id & 7) * cpx + (id >> 3);
  const int nbx = N >> 7;
  const int m0 = (swz / nbx) * 128, n0 = (swz % nbx) * 128;
  const int wm = (wave >> 1) * 64, wn = (wave & 1) * 64;
  f32x4 acc[4][4] = {};

  for (int k0 = 0; k0 < K; k0 += 32) {
    __syncthreads();
#pragma unroll
    for (int t = 0; t < 2; ++t) {
      int r = wave * 32 + t * 16 + (lane >> 2);
      int ca = (lane & 3) ^ ((r >> 1) & 3);
      size_t ga = (size_t)(m0 + r) * K + k0 + ca * 8;
      size_t gb = (size_t)(n0 + r) * K + k0 + ca * 8;
      int lb = (wave * 32 + t * 16) * 32;
      gload16(&Ah_[ga], &sAh[lb]);
      gload16(&Bh_[gb], &sBh[lb]);
    }
    __syncthreads();
    bf16x8 ah[4], bh[4];
#pragma unroll
    for (int t = 0; t < 4; ++t) {
      int Ra = wm + t * 16 + lm;
      int Rb = wn + t * 16 + lm;
      int ca = (lg ^ ((Ra >> 1) & 3)) * 8;
      int cb = (lg ^ ((Rb >> 1) & 3)) * 8;
      ah[t] = *reinterpret_cast<const bf16x8*>(&sAh[Ra * 32 + ca]);
      bh[t] = *reinterpret_cast<const bf16x8*>(&sBh[Rb * 32 + cb]);
    }
#pragma unroll
    for (int mi = 0; mi < 4; ++mi)
#pragma unroll
      for (int ni = 0; ni < 4; ++ni)
        acc[mi][ni] = __builtin_amdgcn_mfma_f32_16x16x32_bf16(ah[mi], bh[ni], acc[mi][ni], 0, 0, 0);
  }
#pragma unroll
  for (int mi = 0; mi < 4; ++mi)
#pragma unroll
    for (int ni = 0; ni < 4; ++ni)
#pragma unroll
      for (int j = 0; j < 4; ++j) {
        int row = m0 + wm + mi * 16 + lg * 4 + j;
        int col = n0 + wn + ni * 16 + lm;
        Cout[(size_t)row * N + col] = acc[mi][ni][j];
      }
}

// ---------------- RoPE in-place on QKV buffer (vectorized x8): Q scaled by log2e/sqrt(HD) ----------------
__global__ __launch_bounds__(256) void rope2_kernel(ushort* __restrict__ QKV,
                                                    const int* __restrict__ pos,
                                                    const float* __restrict__ cosT,
                                                    const float* __restrict__ sinT) {
  int t = blockIdx.x * 256 + threadIdx.x;  // S*1024/8 threads
  int j0 = (t & 7) * 8;
  int hh = (t >> 3) & 15;
  int s = t >> 7;
  int p = pos[s];
  float cs[8], sn[8];
  *reinterpret_cast<float4*>(&cs[0]) = *reinterpret_cast<const float4*>(&cosT[p * 64 + j0]);
  *reinterpret_cast<float4*>(&cs[4]) = *reinterpret_cast<const float4*>(&cosT[p * 64 + j0 + 4]);
  *reinterpret_cast<float4*>(&sn[0]) = *reinterpret_cast<const float4*>(&sinT[p * 64 + j0]);
  *reinterpret_cast<float4*>(&sn[4]) = *reinterpret_cast<const float4*>(&sinT[p * 64 + j0 + 4]);
  size_t base = (size_t)s * LDQ + hh * HEADDIM + j0;
  union u8 { uint4 v; ushort e[8]; };
  u8 qa, qb, ka, kb;
  qa.v = *reinterpret_cast<const uint4*>(&QKV[base]);
  qb.v = *reinterpret_cast<const uint4*>(&QKV[base + 64]);
  ka.v = *reinterpret_cast<const uint4*>(&QKV[base + DMODEL]);
  kb.v = *reinterpret_cast<const uint4*>(&QKV[base + DMODEL + 64]);
  const float scl = 0.12751742f;  // log2(e)/sqrt(128)
#pragma unroll
  for (int e = 0; e < 8; ++e) {
    float q1 = bf2f(qa.e[e]), q2 = bf2f(qb.e[e]);
    float k1 = bf2f(ka.e[e]), k2 = bf2f(kb.e[e]);
    qa.e[e] = f2bf((q1 * cs[e] - q2 * sn[e]) * scl);
    qb.e[e] = f2bf((q2 * cs[e] + q1 * sn[e]) * scl);
    ka.e[e] = f2bf(k1 * cs[e] - k2 * sn[e]);
    kb.e[e] = f2bf(k2 * cs[e] + k1 * sn[e]);
  }
  *reinterpret_cast<uint4*>(&QKV[base]) = qa.v;
  *reinterpret_cast<uint4*>(&QKV[base + 64]) = qb.v;
  *reinterpret_cast<uint4*>(&QKV[base + DMODEL]) = ka.v;
  *reinterpret_cast<uint4*>(&QKV[base + DMODEL + 64]) = kb.v;
}

// ---------------- V transpose: QKV V-columns -> Vt [2048][S] ----------------
__global__ __launch_bounds__(256) void transpose_kernel(const ushort* __restrict__ Vr,
                                                        ushort* __restrict__ Vt) {
  __shared__ __align__(16) ushort tile[64 * 72];
  int tid = threadIdx.x;
  int s0 = blockIdx.x * 64, c0 = blockIdx.y * 64;
#pragma unroll
  for (int it = 0; it < 2; ++it) {
    int i = tid + it * 256;
    int r = i >> 3, c = i & 7;
    *reinterpret_cast<uint4*>(&tile[r * 72 + c * 8]) =
        *reinterpret_cast<const uint4*>(&Vr[(size_t)(s0 + r) * LDQ + c0 + c * 8]);
  }
  __syncthreads();
#pragma unroll
  for (int it = 0; it < 2; ++it) {
    int i = tid + it * 256;
    int cr = i >> 3, sc = i & 7;
    ushort tmp[8];
#pragma unroll
    for (int j = 0; j < 8; ++j) tmp[j] = tile[(sc * 8 + j) * 72 + cr];
    *reinterpret_cast<uint4*>(&Vt[(size_t)(c0 + cr) * S_LEN + s0 + sc * 8]) =
        *reinterpret_cast<uint4*>(tmp);
  }
}

// ---------------- Flash attention v12 = v11 with single-bf16 O output ----------------
__global__ __launch_bounds__(256, 2) void flash12_kernel(const ushort* __restrict__ QKV,
                                                         const ushort* __restrict__ Vt,
                                                         ushort* __restrict__ Oh) {
  __shared__ __align__(16) ushort Kt[2][64 * 128];
  __shared__ __align__(16) ushort Vs[2][128 * 64];
  const int tid = threadIdx.x;             // 0..255
  const int wave = tid >> 6, lane = tid & 63;
  const int lg = lane >> 4, lm = lane & 15;
  const int id = blockIdx.y * gridDim.x + blockIdx.x;  // 0..511
  const int o = (id & 7) * 64 + (id >> 3);             // XCD swizzle (512 = 8*64)
  const int h = o >> 5;
  const int q0 = (o & 31) * 128;

  bf16x8 qh[2][4];
#pragma unroll
  for (int t2 = 0; t2 < 2; ++t2) {
    int qrow = q0 + wave * 32 + t2 * 16 + lm;
#pragma unroll
    for (int kc = 0; kc < 4; ++kc)
      qh[t2][kc] = *reinterpret_cast<const bf16x8*>(
          &QKV[(size_t)qrow * LDQ + h * HEADDIM + kc * 32 + lg * 8]);
  }

  bf16x8 ones;
#pragma unroll
  for (int i = 0; i < 8; ++i) ones[i] = (short)0x3f80;  // bf16 1.0

  auto rho = [](int s) {
    return 32 * ((s >> 4) & 1) + 8 * ((s >> 2) & 3) + 4 * (s >> 5) + (s & 3);
  };
  const ushort* Kb = QKV + DMODEL;  // K columns
  const ushort* pK[4];
  const ushort* pV[4];
  int lbs[4];
#pragma unroll
  for (int k = 0; k < 4; ++k) {
    int ci = k * 256 + wave * 64 + lane;
    int ks = ci >> 4;
    int kcc = (ci & 15) ^ (ks & 7);
    pK[k] = Kb + (size_t)rho(ks) * LDQ + h * HEADDIM + kcc * 8;
    int vd = ci >> 3;
    int vcc = (ci & 7) ^ (vd & 7);
    pV[k] = Vt + (size_t)(h * HEADDIM + vd) * S_LEN + vcc * 8;
    lbs[k] = (k * 256 + wave * 64) * 8;
  }

  f32x4 oacc[2][8] = {};
  f32x4 osum[2] = {};
  float mrun[2];
#pragma unroll
  for (int t2 = 0; t2 < 2; ++t2) mrun[t2] = -3.0e38f;

#pragma unroll
  for (int k = 0; k < 4; ++k) {
    gload16(pK[k], &Kt[0][lbs[k]]);
    gload16(pV[k], &Vs[0][lbs[k]]);
  }
  __syncthreads();

  for (int t = 0; t < S_LEN / 64; ++t) {
    const int cur = t & 1;
    if (t < S_LEN / 64 - 1) {
      const size_t koff = (size_t)(t + 1) * 64;
#pragma unroll
      for (int k = 0; k < 4; ++k) {
        gload16(pK[k] + koff * LDQ, &Kt[cur ^ 1][lbs[k]]);
        gload16(pV[k] + koff, &Vs[cur ^ 1][lbs[k]]);
      }
    }
    const ushort* Kc = &Kt[cur][0];
    const ushort* Vc = &Vs[cur][0];

    // QK^T swapped
    f32x4 st[2][4] = {};
    __builtin_amdgcn_s_setprio(1);
#pragma unroll
    for (int nf = 0; nf < 4; ++nf)
#pragma unroll
      for (int kc = 0; kc < 4; ++kc) {
        int pc = (kc * 4 + lg) ^ (lm & 7);
        bf16x8 kfrag = *reinterpret_cast<const bf16x8*>(&Kc[(nf * 16 + lm) * 128 + pc * 8]);
        st[0][nf] = __builtin_amdgcn_mfma_f32_16x16x32_bf16(kfrag, qh[0][kc], st[0][nf], 0, 0, 0);
        st[1][nf] = __builtin_amdgcn_mfma_f32_16x16x32_bf16(kfrag, qh[1][kc], st[1][nf], 0, 0, 0);
      }
    __builtin_amdgcn_s_setprio(0);

    // row max
    float m16[2];
#pragma unroll
    for (int t2 = 0; t2 < 2; ++t2) {
      float m = fmaxf(st[t2][0][0], st[t2][0][1]);
      m = fmaxf(fmaxf(m, st[t2][0][2]), st[t2][0][3]);
      m = fmaxf(fmaxf(m, st[t2][1][0]), st[t2][1][1]);
      m = fmaxf(fmaxf(m, st[t2][1][2]), st[t2][1][3]);
      m = fmaxf(fmaxf(m, st[t2][2][0]), st[t2][2][1]);
      m = fmaxf(fmaxf(m, st[t2][2][2]), st[t2][2][3]);
      m = fmaxf(fmaxf(m, st[t2][3][0]), st[t2][3][1]);
      m = fmaxf(fmaxf(m, st[t2][3][2]), st[t2][3][3]);
      m = fmaxf(m, __shfl_xor(m, 16));
      m = fmaxf(m, __shfl_xor(m, 32));
      m16[t2] = m;
    }

    // defer-max rescale (exp2 domain, thr 11.5 ~= 8*log2e)
    bool grow = (m16[0] > mrun[0] + 11.5f) || (m16[1] > mrun[1] + 11.5f);
    if (__any(grow)) {
#pragma unroll
      for (int t2 = 0; t2 < 2; ++t2) {
        float mn = fmaxf(mrun[t2], m16[t2]);
        float scl = fexp2(mrun[t2] - mn);
        mrun[t2] = mn;
        float sj[4];
#pragma unroll
        for (int j = 0; j < 4; ++j) sj[j] = __shfl(scl, lg * 4 + j);
#pragma unroll
        for (int j = 0; j < 4; ++j) osum[t2][j] *= sj[j];
#pragma unroll
        for (int nb = 0; nb < 8; ++nb)
#pragma unroll
          for (int j = 0; j < 4; ++j) oacc[t2][nb][j] *= sj[j];
      }
    }

    // P = exp2(S2 - m2) via raw v_exp_f32
#pragma unroll
    for (int t2 = 0; t2 < 2; ++t2)
#pragma unroll
      for (int nf = 0; nf < 4; ++nf)
#pragma unroll
        for (int j = 0; j < 4; ++j)
          st[t2][nf][j] = fexp2(st[t2][nf][j] - mrun[t2]);

    // pack PV A-frags
    bf16x8 pa[2][2];
#pragma unroll
    for (int t2 = 0; t2 < 2; ++t2)
#pragma unroll
      for (int kk = 0; kk < 2; ++kk) {
        union { unsigned int u[4]; bf16x8 v; } w_;
        w_.u[0] = cvtpk(st[t2][kk][0], st[t2][kk][1]);
        w_.u[1] = cvtpk(st[t2][kk][2], st[t2][kk][3]);
        w_.u[2] = cvtpk(st[t2][2 + kk][0], st[t2][2 + kk][1]);
        w_.u[3] = cvtpk(st[t2][2 + kk][2], st[t2][2 + kk][3]);
        pa[t2][kk] = w_.v;
      }

    // PV + row-sum via ones-MFMA
    __builtin_amdgcn_s_setprio(1);
#pragma unroll
    for (int t2 = 0; t2 < 2; ++t2) {
      osum[t2] = __builtin_amdgcn_mfma_f32_16x16x32_bf16(pa[t2][0], ones, osum[t2], 0, 0, 0);
      osum[t2] = __builtin_amdgcn_mfma_f32_16x16x32_bf16(pa[t2][1], ones, osum[t2], 0, 0, 0);
    }
#pragma unroll
    for (int nb = 0; nb < 8; ++nb)
#pragma unroll
      for (int kk = 0; kk < 2; ++kk) {
        int pc = (kk * 4 + lg) ^ (lm & 7);
        bf16x8 vfrag = *reinterpret_cast<const bf16x8*>(&Vc[(nb * 16 + lm) * 64 + pc * 8]);
        oacc[0][nb] = __builtin_amdgcn_mfma_f32_16x16x32_bf16(pa[0][kk], vfrag, oacc[0][nb], 0, 0, 0);
        oacc[1][nb] = __builtin_amdgcn_mfma_f32_16x16x32_bf16(pa[1][kk], vfrag, oacc[1][nb], 0, 0, 0);
      }
    __builtin_amdgcn_s_setprio(0);

    __syncthreads();
  }

  // epilogue: single bf16 O
#pragma unroll
  for (int t2 = 0; t2 < 2; ++t2) {
    float linv[4];
#pragma unroll
    for (int j = 0; j < 4; ++j) linv[j] = 1.0f / osum[t2][j];
#pragma unroll
    for (int nb = 0; nb < 8; ++nb)
#pragma unroll
      for (int j = 0; j < 4; ++j) {
        int row = q0 + wave * 32 + t2 * 16 + lg * 4 + j;
        int col = h * HEADDIM + nb * 16 + lm;
        Oh[(size_t)row * DMODEL + col] = f2bf(oacc[t2][nb][j] * linv[j]);
      }
  }
}

extern "C" void kernel_launch(void* const* d_in, const int* in_sizes, int n_in,
                              void* d_out, int out_size, void* d_ws, size_t ws_size,
                              hipStream_t stream) {
  (void)in_sizes; (void)n_in; (void)out_size; (void)ws_size;
  const float* X  = (const float*)d_in[0];
  const float* Wq = (const float*)d_in[1];
  const float* Wk = (const float*)d_in[2];
  const float* Wv = (const float*)d_in[3];
  const float* Wo = (const float*)d_in[4];
  const int* pos  = (const int*)d_in[5];
  float* out = (float*)d_out;

  ushort* wb = (ushort*)d_ws;
  const size_t SD = (size_t)S_LEN * DMODEL;       // 8388608 elements
  const size_t DD = (size_t)DMODEL * DMODEL;      // 4194304 elements

  ushort* Xh   = wb;                 // slot0
  ushort* QKV  = wb + 2 * SD;        // slots 2-4: [4096][6144]
  ushort* Vt   = wb + 5 * SD;        // slot5: [2048][4096]
  ushort* W0h  = wb + 6 * SD;        // Wo bf16
  ushort* Wqkv = wb + 7 * SD;        // [6144][2048]
  float* cosT  = (float*)(wb + 9 * SD);
  float* sinT  = cosT + (size_t)S_LEN * 64;
  ushort* OhB  = Wqkv;               // reuse after QKV GEMM done

  rope_table_kernel<<<S_LEN * 64 / 256, 256, 0, stream>>>(cosT, sinT);
  convert_kernel<<<SD / 1024, 256, 0, stream>>>(X, Xh);
  prep_weights<<<dim3(DD / 1024, 4), 256, 0, stream>>>(Wq, Wk, Wv, Wo, Wqkv, W0h);

  gemm_qkv<<<dim3(LDQ / 128, S_LEN / 128), 256, 0, stream>>>(Xh, Wqkv, QKV, S_LEN, LDQ, DMODEL);

  rope2_kernel<<<(S_LEN * 1024 / 8) / 256, 256, 0, stream>>>(QKV, pos, cosT, sinT);
  transpose_kernel<<<dim3(S_LEN / 64, DMODEL / 64), 256, 0, stream>>>(QKV + 2 * DMODEL, Vt);

  flash12_kernel<<<dim3(32, 16), 256, 0, stream>>>(QKV, Vt, OhB);

  dim3 gemmGrid(DMODEL / 128, S_LEN / 128);
  gemm1o<<<gemmGrid, 256, 0, stream>>>(OhB, W0h, out, S_LEN, DMODEL, DMODEL);
}